// Round 3
// baseline (7674.737 us; speedup 1.0000x reference)
//
#include <hip/hip_runtime.h>

#define S_ 50
#define B_ 64
#define T_ 32
#define E_ 512
#define H_ 1024
#define C_ 1024
#define V_ 32000
#define TS_ 31            // T-1 steps
#define NR_ 1984          // TS_*B_ rows
#define NBLK_ 256         // persistent-loop grid size

typedef __attribute__((ext_vector_type(8))) short s8v;   // 8 x bf16 bits
typedef __attribute__((ext_vector_type(4))) float f4v;   // MFMA acc

static __device__ __forceinline__ float b2f(ushort u) {
  unsigned x = ((unsigned)u) << 16; float f; __builtin_memcpy(&f, &x, 4); return f;
}
static __device__ __forceinline__ ushort f2b(float f) {
  unsigned x; __builtin_memcpy(&x, &f, 4);
  x = x + 0x7FFFu + ((x >> 16) & 1u);
  return (ushort)(x >> 16);
}
static __device__ __forceinline__ float sigm(float x) { return 1.f / (1.f + __expf(-x)); }

// A-frag: lane holds row (l&15), k = kb + 8*(l>>4) + j   (16B contiguous load)
// B-frag: same pattern on the (N x K) row-major weight.
static __device__ __forceinline__ s8v ldfrag(const ushort* base, int ld, int row0, int kb, int lane) {
  const ushort* p = base + (size_t)(row0 + (lane & 15)) * ld + (kb + ((lane >> 4) << 3));
  return *reinterpret_cast<const s8v*>(p);
}

// ---------------- conversions / gathers ----------------

__global__ void k_convert(const float* __restrict__ s, ushort* __restrict__ d, int n) {
  int i = (blockIdx.x * 256 + threadIdx.x) * 4;
  if (i >= n) return;
  float4 v = *reinterpret_cast<const float4*>(s + i);
  ushort4 o; o.x = f2b(v.x); o.y = f2b(v.y); o.z = f2b(v.z); o.w = f2b(v.w);
  *reinterpret_cast<ushort4*>(d + i) = o;
}

// W_c2h (H x C) -> bf16 transposed (C x H)
__global__ void k_convert_T(const float* __restrict__ s, ushort* __restrict__ d) {
  int gid = blockIdx.x * 256 + threadIdx.x;
  int h = gid & 1023, c = gid >> 10;
  d[(size_t)c * 1024 + h] = f2b(s[(size_t)h * 1024 + c]);
}

__global__ void k_gather(const int* __restrict__ y, const float* __restrict__ emb,
                         ushort* __restrict__ xb) {
  int gid = blockIdx.x * 256 + threadIdx.x;
  if (gid >= NR_ * (E_ / 4)) return;
  int i = gid >> 7;
  int c = (gid & 127) << 2;
  int idx = y[i];
  float4 v = make_float4(0.f, 0.f, 0.f, 0.f);
  if (idx != 0) v = *reinterpret_cast<const float4*>(emb + (size_t)idx * E_ + c);
  ushort4 o; o.x = f2b(v.x); o.y = f2b(v.y); o.z = f2b(v.z); o.w = f2b(v.w);
  *reinterpret_cast<ushort4*>(xb + (size_t)i * E_ + c) = o;
}

// ---------------- generic GEMM: out[m,n] = sum_k A[m,k]*B[n,k] (+bias) (opt tanh) ----------------
__global__ void gemm_bt(const ushort* __restrict__ A, const ushort* __restrict__ Bm,
                        const float* __restrict__ bias, float* __restrict__ outF,
                        ushort* __restrict__ outB, int M, int N, int K, int act) {
  int l = threadIdx.x & 63, w = threadIdx.x >> 6;
  int m0 = blockIdx.y * 64 + w * 16;
  int n0 = blockIdx.x * 64;
  f4v acc[4] = {{0.f,0.f,0.f,0.f},{0.f,0.f,0.f,0.f},{0.f,0.f,0.f,0.f},{0.f,0.f,0.f,0.f}};
  for (int kb = 0; kb < K; kb += 32) {
    s8v a = ldfrag(A, K, m0, kb, l);
#pragma unroll
    for (int nt = 0; nt < 4; nt++) {
      s8v b = ldfrag(Bm, K, n0 + nt * 16, kb, l);
      acc[nt] = __builtin_amdgcn_mfma_f32_16x16x32_bf16(a, b, acc[nt], 0, 0, 0);
    }
  }
  int rb = (l >> 4) * 4;
  int col = l & 15;
#pragma unroll
  for (int nt = 0; nt < 4; nt++) {
    int n = n0 + nt * 16 + col;
    float bv = bias ? bias[n] : 0.f;
#pragma unroll
    for (int i = 0; i < 4; i++) {
      int m = m0 + rb + i;
      float v = acc[nt][i] + bv;
      if (act) v = tanhf(v);
      size_t o = (size_t)m * N + n;
      if (outF) outF[o] = v;
      if (outB) outB[o] = f2b(v);
    }
  }
}

// ---------------- persistent sequential loop (cooperative) ----------------

struct LoopP {
  const ushort* whh0b; const ushort* gi0b; const ushort* wh2cb; const ushort* whh1b;
  const ushort* wcombb; const ushort* ctxpb; const ushort* ctxb;
  const float* bhh0; const float* bih1; const float* bhh1; const float* wmlp;
  const float* h0f; const ushort* h0b;
  float* h1f; ushort* h1b; float* hidf; float* gh1f; ushort* zrawb;
  float* H2f; ushort* H2b;
  unsigned* bar;   // [cnt, gen]
};

// grid barrier: release(wbl2) -> arrive -> spin -> acquire(inv). bar memset to 0 per launch.
static __device__ __forceinline__ void gbar(unsigned* bar) {
  __syncthreads();                    // drains each wave's vmcnt -> stores are in local L2
  if (threadIdx.x == 0) {
    __threadfence();                  // agent fence: writeback local L2 (release)
    unsigned* cnt = bar;
    unsigned* gen = bar + 1;
    unsigned g = __hip_atomic_load(gen, __ATOMIC_RELAXED, __HIP_MEMORY_SCOPE_AGENT);
    unsigned v = __hip_atomic_fetch_add(cnt, 1u, __ATOMIC_ACQ_REL, __HIP_MEMORY_SCOPE_AGENT);
    if (v == (unsigned)NBLK_ - 1u) {
      __hip_atomic_store(cnt, 0u, __ATOMIC_RELAXED, __HIP_MEMORY_SCOPE_AGENT);
      __hip_atomic_fetch_add(gen, 1u, __ATOMIC_RELEASE, __HIP_MEMORY_SCOPE_AGENT);
    } else {
      while (__hip_atomic_load(gen, __ATOMIC_RELAXED, __HIP_MEMORY_SCOPE_AGENT) == g)
        __builtin_amdgcn_s_sleep(2);
    }
    __builtin_amdgcn_fence(__ATOMIC_ACQUIRE, "agent");   // invalidate local caches
  }
  __syncthreads();
}

__global__ __launch_bounds__(256) void k_loop(LoopP p) {
  const int tid = threadIdx.x;
  const int blk = blockIdx.x;
  const int l = tid & 63, w = tid >> 6;
  __shared__ float hs[C_];
  __shared__ float sc[S_];
  __shared__ float al[S_];

  for (int t = 0; t < TS_; t++) {
    const float*  hpf = t ? (p.H2f + (size_t)(t - 1) * B_ * H_) : p.h0f;
    const ushort* hpb = t ? (p.H2b + (size_t)(t - 1) * B_ * H_) : p.h0b;
    const ushort* gi0t = p.gi0b + (size_t)t * B_ * 3 * H_;

    // ---- phase A: GRU0 -> h1 ----
    if (blk < 64) {
      int j = blk * 16, m0 = w * 16;
      f4v aR = {0.f,0.f,0.f,0.f}, aZ = {0.f,0.f,0.f,0.f}, aN = {0.f,0.f,0.f,0.f};
#pragma unroll 4
      for (int kb = 0; kb < H_; kb += 32) {
        s8v a  = ldfrag(hpb, H_, m0, kb, l);
        s8v bR = ldfrag(p.whh0b, H_, j, kb, l);
        s8v bZ = ldfrag(p.whh0b, H_, H_ + j, kb, l);
        s8v bN = ldfrag(p.whh0b, H_, 2 * H_ + j, kb, l);
        aR = __builtin_amdgcn_mfma_f32_16x16x32_bf16(a, bR, aR, 0, 0, 0);
        aZ = __builtin_amdgcn_mfma_f32_16x16x32_bf16(a, bZ, aZ, 0, 0, 0);
        aN = __builtin_amdgcn_mfma_f32_16x16x32_bf16(a, bN, aN, 0, 0, 0);
      }
      int rb = (l >> 4) * 4, c = j + (l & 15);
#pragma unroll
      for (int i = 0; i < 4; i++) {
        int m = m0 + rb + i;
        const ushort* gi = gi0t + (size_t)m * (3 * H_);
        float gir = b2f(gi[c]), giz = b2f(gi[H_ + c]), gin = b2f(gi[2 * H_ + c]);
        float ghr = aR[i] + p.bhh0[c], ghz = aZ[i] + p.bhh0[H_ + c], ghn = aN[i] + p.bhh0[2 * H_ + c];
        float r = sigm(gir + ghr);
        float zg = sigm(giz + ghz);
        float nn = tanhf(gin + r * ghn);
        float hp = hpf[(size_t)m * H_ + c];
        float h1 = (1.f - zg) * nn + zg * hp;
        p.h1f[(size_t)m * H_ + c] = h1;
        p.h1b[(size_t)m * H_ + c] = f2b(h1);
      }
    }
    gbar(p.bar);

    // ---- phase B: hid = h1@Wh2c.T (blk 0-63) | gh1 = h1@Whh1.T (blk 64-255) ----
    {
      int g = blk * 16;
      const ushort* Bm; int brow, ldd, dcol; float* dst;
      if (g < C_) { Bm = p.wh2cb; brow = g; dst = p.hidf; ldd = C_; dcol = g; }
      else { Bm = p.whh1b; brow = g - C_; dst = p.gh1f; ldd = 3 * H_; dcol = g - C_; }
      int m0 = w * 16;
      f4v acc = {0.f,0.f,0.f,0.f};
#pragma unroll 4
      for (int kb = 0; kb < H_; kb += 32) {
        s8v a = ldfrag(p.h1b, H_, m0, kb, l);
        s8v b = ldfrag(Bm, H_, brow, kb, l);
        acc = __builtin_amdgcn_mfma_f32_16x16x32_bf16(a, b, acc, 0, 0, 0);
      }
      int rb = (l >> 4) * 4, c = dcol + (l & 15);
#pragma unroll
      for (int i = 0; i < 4; i++) {
        int m = m0 + rb + i;
        dst[(size_t)m * ldd + c] = acc[i];
      }
    }
    gbar(p.bar);

    // ---- phase C: attention -> z_raw ----
    if (blk < 64) {
      int b = blk;
      for (int c = tid; c < C_; c += 256) hs[c] = p.hidf[(size_t)b * C_ + c];
      __syncthreads();
      for (int s = w; s < S_; s += 4) {
        const ushort* row = p.ctxpb + ((size_t)s * B_ + b) * C_;
        float acc = 0.f;
        for (int c = l; c < C_; c += 64) acc += tanhf(b2f(row[c]) + hs[c]) * p.wmlp[c];
        for (int m = 32; m; m >>= 1) acc += __shfl_xor(acc, m, 64);
        if (l == 0) sc[s] = acc;
      }
      __syncthreads();
      float mx = -1e30f;
      for (int s = 0; s < S_; s++) mx = fmaxf(mx, sc[s]);
      float sm = 0.f;
      for (int s = 0; s < S_; s++) sm += __expf(sc[s] - mx);
      if (tid < S_) al[tid] = __expf(sc[tid] - mx) / sm;
      __syncthreads();
      int c0 = tid * 4;
      float a0 = 0.f, a1 = 0.f, a2 = 0.f, a3 = 0.f;
      for (int s = 0; s < S_; s++) {
        float a = al[s];
        ushort4 cv = *reinterpret_cast<const ushort4*>(p.ctxb + ((size_t)s * B_ + b) * C_ + c0);
        a0 += a * b2f(cv.x); a1 += a * b2f(cv.y); a2 += a * b2f(cv.z); a3 += a * b2f(cv.w);
      }
      ushort4 o; o.x = f2b(a0); o.y = f2b(a1); o.z = f2b(a2); o.w = f2b(a3);
      *reinterpret_cast<ushort4*>(p.zrawb + (size_t)b * C_ + c0) = o;
    }
    gbar(p.bar);

    // ---- phase D: GRU1 -> h2 (=H2[t]) ----
    if (blk < 64) {
      int j = blk * 16, m0 = w * 16;
      float* h2f = p.H2f + (size_t)t * B_ * H_;
      ushort* h2b = p.H2b + (size_t)t * B_ * H_;
      f4v aR = {0.f,0.f,0.f,0.f}, aZ = {0.f,0.f,0.f,0.f}, aN = {0.f,0.f,0.f,0.f};
#pragma unroll 4
      for (int kb = 0; kb < C_; kb += 32) {
        s8v a  = ldfrag(p.zrawb, C_, m0, kb, l);
        s8v bR = ldfrag(p.wcombb, C_, j, kb, l);
        s8v bZ = ldfrag(p.wcombb, C_, H_ + j, kb, l);
        s8v bN = ldfrag(p.wcombb, C_, 2 * H_ + j, kb, l);
        aR = __builtin_amdgcn_mfma_f32_16x16x32_bf16(a, bR, aR, 0, 0, 0);
        aZ = __builtin_amdgcn_mfma_f32_16x16x32_bf16(a, bZ, aZ, 0, 0, 0);
        aN = __builtin_amdgcn_mfma_f32_16x16x32_bf16(a, bN, aN, 0, 0, 0);
      }
      int rb = (l >> 4) * 4, c = j + (l & 15);
#pragma unroll
      for (int i = 0; i < 4; i++) {
        int m = m0 + rb + i;
        float gir = aR[i] + p.bih1[c], giz = aZ[i] + p.bih1[H_ + c], gin = aN[i] + p.bih1[2 * H_ + c];
        const float* gh = p.gh1f + (size_t)m * (3 * H_);
        float ghr = gh[c] + p.bhh1[c], ghz = gh[H_ + c] + p.bhh1[H_ + c], ghn = gh[2 * H_ + c] + p.bhh1[2 * H_ + c];
        float r = sigm(gir + ghr);
        float zg = sigm(giz + ghz);
        float nn = tanhf(gin + r * ghn);
        float h1 = p.h1f[(size_t)m * H_ + c];
        float h2 = (1.f - zg) * nn + zg * h1;
        h2f[(size_t)m * H_ + c] = h2;
        h2b[(size_t)m * H_ + c] = f2b(h2);
      }
    }
    gbar(p.bar);
  }
}

// ---------------- epilogue: streaming LSE over vocab, v2 ----------------
// grid (40 col-chunks x 16 rowblocks of 128), block=512.  A-frags in regs,
// B reg-staged into XOR-swizzled LDS double-buffer (T2 both-sides involution).
#define LSE_NCH 40
#define LSE_TILES 50    // 16-col tiles per chunk (40*50*16 = 32000)

__global__ __launch_bounds__(512) void k_lse2(const ushort* __restrict__ logitb,
                                              const ushort* __restrict__ wopb,
                                              const float* __restrict__ bop,
                                              float* __restrict__ part) {
  __shared__ ushort Bs[2][16 * E_];   // 2 x 16KB (16 rows x 1024B)
  int tid = threadIdx.x, l = tid & 63, w = tid >> 6;
  int r0 = blockIdx.y * 128 + w * 16;
  int c0 = blockIdx.x * (LSE_TILES * 16);
  int arow = r0 + (l & 15);
  bool aok = arow < NR_;

  // A-frags: tile-invariant, hoisted to regs (16 x 16B = 64 VGPR)
  s8v afr[16];
#pragma unroll
  for (int kk = 0; kk < 16; kk++) {
    s8v z = {0,0,0,0,0,0,0,0};
    afr[kk] = aok ? *reinterpret_cast<const s8v*>(logitb + (size_t)arow * E_ + kk * 32 + ((l >> 4) << 3)) : z;
  }

  // B staging addressing: thread tid owns row=tid>>5, 32B chunk (tid&31)*32
  const int srow = tid >> 5;
  const int scb = (tid & 31) * 32;
  const unsigned sxr = (unsigned)((srow & 7) << 4);
  char* sdst0 = (char*)&Bs[0][0] + srow * 1024;
  char* sdst1 = (char*)&Bs[1][0] + srow * 1024;

  // B read addressing (same XOR involution)
  const int brow = l & 15;
  const unsigned lanep = (unsigned)((l >> 4) << 4);
  const unsigned xorv = (unsigned)((brow & 7) << 4);
  const char* bbase0 = (const char*)&Bs[0][0] + brow * 1024;
  const char* bbase1 = (const char*)&Bs[1][0] + brow * 1024;

  f4v mr = {-1e30f, -1e30f, -1e30f, -1e30f};
  f4v sr = {0.f, 0.f, 0.f, 0.f};

  // prologue: stage tile 0 into buf 0
  {
    const char* src = (const char*)(wopb + (size_t)(c0 + srow) * E_) + scb;
    s8v g0 = *reinterpret_cast<const s8v*>(src);
    s8v g1 = *reinterpret_cast<const s8v*>(src + 16);
    *reinterpret_cast<s8v*>(sdst0 + ((unsigned)scb ^ sxr)) = g0;
    *reinterpret_cast<s8v*>(sdst0 + (((unsigned)scb + 16u) ^ sxr)) = g1;
  }
  __syncthreads();

  for (int tt = 0; tt < LSE_TILES; tt++) {
    int cur = tt & 1;
    bool more = (tt + 1) < LSE_TILES;
    s8v g0, g1;
    if (more) {   // issue next tile's global loads before compute (latency hides under MFMA)
      const char* src = (const char*)(wopb + (size_t)(c0 + (tt + 1) * 16 + srow) * E_) + scb;
      g0 = *reinterpret_cast<const s8v*>(src);
      g1 = *reinterpret_cast<const s8v*>(src + 16);
    }
    const char* bbase = cur ? bbase1 : bbase0;
    f4v acc = {0.f, 0.f, 0.f, 0.f};
#pragma unroll
    for (int kk = 0; kk < 16; kk++) {
      unsigned off = ((unsigned)(kk * 64) + lanep) ^ xorv;
      s8v b = *reinterpret_cast<const s8v*>(bbase + off);
      acc = __builtin_amdgcn_mfma_f32_16x16x32_bf16(afr[kk], b, acc, 0, 0, 0);
    }
    float bv = bop[c0 + tt * 16 + (l & 15)];
#pragma unroll
    for (int i = 0; i < 4; i++) {
      float v = acc[i] + bv;
      if (v <= mr[i]) {
        sr[i] += __expf(v - mr[i]);
      } else {
        sr[i] = sr[i] * __expf(mr[i] - v) + 1.f;
        mr[i] = v;
      }
    }
    if (more) {   // buf[cur^1] was last read before the barrier that ended iter tt-1
      char* sdst = cur ? sdst0 : sdst1;
      *reinterpret_cast<s8v*>(sdst + ((unsigned)scb ^ sxr)) = g0;
      *reinterpret_cast<s8v*>(sdst + (((unsigned)scb + 16u) ^ sxr)) = g1;
      __syncthreads();
    }
  }

  // combine across the 16 lanes sharing each row group
  for (int sh = 1; sh < 16; sh <<= 1) {
#pragma unroll
    for (int i = 0; i < 4; i++) {
      float om = __shfl_xor(mr[i], sh, 64);
      float os = __shfl_xor(sr[i], sh, 64);
      float mn = fmaxf(mr[i], om);
      sr[i] = sr[i] * __expf(mr[i] - mn) + os * __expf(om - mn);
      mr[i] = mn;
    }
  }
  if ((l & 15) == 0) {
#pragma unroll
    for (int i = 0; i < 4; i++) {
      int row = r0 + (l >> 4) * 4 + i;
      if (row < NR_) {
        size_t o = ((size_t)row * LSE_NCH + blockIdx.x) * 2;
        part[o] = mr[i];
        part[o + 1] = sr[i];
      }
    }
  }
}

// per-row: combine chunk partials -> lse; target dot (fp32 W_op); masked nll
__global__ void k_final(const float* __restrict__ part, const ushort* __restrict__ logitb,
                        const float* __restrict__ Wop, const float* __restrict__ bop,
                        const int* __restrict__ y, float* __restrict__ nll) {
  int i = blockIdx.x * 256 + threadIdx.x;
  if (i >= NR_) return;
  float m = -1e30f;
  for (int c = 0; c < LSE_NCH; c++) m = fmaxf(m, part[((size_t)i * LSE_NCH + c) * 2]);
  float s = 0.f;
  for (int c = 0; c < LSE_NCH; c++) {
    size_t o = ((size_t)i * LSE_NCH + c) * 2;
    s += part[o + 1] * __expf(part[o] - m);
  }
  float lse = m + logf(s);
  int tgt = y[i + B_];
  float v = 0.f;
  if (tgt != 0) {
    const ushort* lr = logitb + (size_t)i * E_;
    const float* wr = Wop + (size_t)tgt * E_;
    float dot = 0.f;
    for (int k = 0; k < E_; k++) dot += b2f(lr[k]) * wr[k];
    dot += bop[tgt];
    v = lse - dot;
  }
  nll[i] = v;
}

__global__ void k_reduce(const float* __restrict__ nll, float* __restrict__ out) {
  __shared__ float sh[256];
  float a = 0.f;
  for (int i = threadIdx.x; i < NR_; i += 256) a += nll[i];
  sh[threadIdx.x] = a;
  __syncthreads();
  for (int s = 128; s; s >>= 1) {
    if (threadIdx.x < s) sh[threadIdx.x] += sh[threadIdx.x + s];
    __syncthreads();
  }
  if (threadIdx.x == 0) out[0] = sh[0];
}

// ---------------- host ----------------

extern "C" void kernel_launch(void* const* d_in, const int* in_sizes, int n_in,
                              void* d_out, int out_size, void* d_ws, size_t ws_size,
                              hipStream_t stream) {
  const float* ctx  = (const float*)d_in[0];
  const int*   y    = (const int*)d_in[1];
  const float* emb  = (const float*)d_in[2];
  const float* Wih0 = (const float*)d_in[3];
  const float* Whh0 = (const float*)d_in[4];
  const float* bih0 = (const float*)d_in[5];
  const float* bhh0 = (const float*)d_in[6];
  const float* Wih1 = (const float*)d_in[7];
  const float* Whh1 = (const float*)d_in[8];
  const float* bih1 = (const float*)d_in[9];
  const float* bhh1 = (const float*)d_in[10];
  const float* Wc2c = (const float*)d_in[11];
  const float* Wh2c = (const float*)d_in[12];
  const float* wmlp = (const float*)d_in[13];
  const float* Wc2h = (const float*)d_in[14];
  const float* Who  = (const float*)d_in[15];
  const float* bho  = (const float*)d_in[16];
  const float* Wop  = (const float*)d_in[17];
  const float* bop  = (const float*)d_in[18];

  char* ws = (char*)d_ws;
  size_t off = 0;
  auto alloc = [&](size_t bytes) { void* p = ws + off; off += (bytes + 255) & ~size_t(255); return p; };

  ushort* ctxb   = (ushort*)alloc((size_t)S_ * B_ * C_ * 2);
  ushort* wih0b  = (ushort*)alloc((size_t)3 * H_ * E_ * 2);
  ushort* whh0b  = (ushort*)alloc((size_t)3 * H_ * H_ * 2);
  ushort* wh2cb  = (ushort*)alloc((size_t)C_ * H_ * 2);
  ushort* wc2hT  = (ushort*)alloc((size_t)C_ * H_ * 2);
  ushort* wih1b  = (ushort*)alloc((size_t)3 * H_ * H_ * 2);
  ushort* whh1b  = (ushort*)alloc((size_t)3 * H_ * H_ * 2);
  ushort* whob   = (ushort*)alloc((size_t)E_ * H_ * 2);
  ushort* wopb   = (ushort*)alloc((size_t)V_ * E_ * 2);
  ushort* wc2cb  = (ushort*)alloc((size_t)C_ * C_ * 2);
  ushort* wcombb = (ushort*)alloc((size_t)3 * H_ * C_ * 2);
  ushort* xb     = (ushort*)alloc((size_t)NR_ * E_ * 2);
  ushort* gi0b   = (ushort*)alloc((size_t)NR_ * 3 * H_ * 2);
  ushort* ctxpb  = (ushort*)alloc((size_t)S_ * B_ * C_ * 2);
  float*  H2f    = (float*)alloc((size_t)TS_ * B_ * H_ * 4);
  ushort* H2b    = (ushort*)alloc((size_t)TS_ * B_ * H_ * 2);
  float*  h0f    = (float*)alloc((size_t)B_ * H_ * 4);
  ushort* h0b    = (ushort*)alloc((size_t)B_ * H_ * 2);
  float*  h1f    = (float*)alloc((size_t)B_ * H_ * 4);
  ushort* h1b    = (ushort*)alloc((size_t)B_ * H_ * 2);
  float*  hidf   = (float*)alloc((size_t)B_ * C_ * 4);
  float*  gh1f   = (float*)alloc((size_t)B_ * 3 * H_ * 4);
  ushort* zrawb  = (ushort*)alloc((size_t)B_ * C_ * 2);
  ushort* logitb = (ushort*)alloc((size_t)NR_ * E_ * 2);
  float*  part   = (float*)alloc((size_t)2048 * LSE_NCH * 2 * 4);
  float*  nllb   = (float*)alloc((size_t)2048 * 4);
  unsigned* bar  = (unsigned*)alloc(256);
  (void)ws_size; (void)in_sizes; (void)n_in; (void)out_size;

  (void)hipMemsetAsync(h0f, 0, (size_t)B_ * H_ * 4, stream);
  (void)hipMemsetAsync(h0b, 0, (size_t)B_ * H_ * 2, stream);
  (void)hipMemsetAsync(bar, 0, 256, stream);

  auto cgrid = [](int n) { return dim3((unsigned)((n / 4 + 255) / 256)); };
  k_convert<<<cgrid(S_ * B_ * C_), 256, 0, stream>>>(ctx, ctxb, S_ * B_ * C_);
  k_convert<<<cgrid(3 * H_ * E_), 256, 0, stream>>>(Wih0, wih0b, 3 * H_ * E_);
  k_convert<<<cgrid(3 * H_ * H_), 256, 0, stream>>>(Whh0, whh0b, 3 * H_ * H_);
  k_convert<<<cgrid(C_ * H_), 256, 0, stream>>>(Wh2c, wh2cb, C_ * H_);
  k_convert<<<cgrid(3 * H_ * H_), 256, 0, stream>>>(Wih1, wih1b, 3 * H_ * H_);
  k_convert<<<cgrid(3 * H_ * H_), 256, 0, stream>>>(Whh1, whh1b, 3 * H_ * H_);
  k_convert<<<cgrid(E_ * H_), 256, 0, stream>>>(Who, whob, E_ * H_);
  k_convert<<<cgrid(V_ * E_), 256, 0, stream>>>(Wop, wopb, V_ * E_);
  k_convert<<<cgrid(C_ * C_), 256, 0, stream>>>(Wc2c, wc2cb, C_ * C_);
  k_convert_T<<<dim3(4096), 256, 0, stream>>>(Wc2h, wc2hT);

  k_gather<<<dim3((NR_ * (E_ / 4) + 255) / 256), 256, 0, stream>>>(y, emb, xb);

  gemm_bt<<<dim3(3 * H_ / 64, NR_ / 64), 256, 0, stream>>>(xb, wih0b, bih0, nullptr, gi0b,
                                                           NR_, 3 * H_, E_, 0);
  gemm_bt<<<dim3(C_ / 64, S_ * B_ / 64), 256, 0, stream>>>(ctxb, wc2cb, nullptr, nullptr, ctxpb,
                                                           S_ * B_, C_, C_, 0);
  gemm_bt<<<dim3(C_ / 64, 3 * H_ / 64), 256, 0, stream>>>(wih1b, wc2hT, nullptr, nullptr, wcombb,
                                                          3 * H_, C_, H_, 0);

  // persistent cooperative sequential loop
  LoopP p;
  p.whh0b = whh0b; p.gi0b = gi0b; p.wh2cb = wh2cb; p.whh1b = whh1b;
  p.wcombb = wcombb; p.ctxpb = ctxpb; p.ctxb = ctxb;
  p.bhh0 = bhh0; p.bih1 = bih1; p.bhh1 = bhh1; p.wmlp = wmlp;
  p.h0f = h0f; p.h0b = h0b;
  p.h1f = h1f; p.h1b = h1b; p.hidf = hidf; p.gh1f = gh1f; p.zrawb = zrawb;
  p.H2f = H2f; p.H2b = H2b; p.bar = bar;
  void* args[] = { (void*)&p };
  (void)hipLaunchCooperativeKernel(k_loop, dim3(NBLK_), dim3(256), args, 0, stream);

  gemm_bt<<<dim3(E_ / 64, NR_ / 64), 256, 0, stream>>>(H2b, whob, bho, nullptr, logitb,
                                                       NR_, E_, H_, 1);
  k_lse2<<<dim3(LSE_NCH, 16), 512, 0, stream>>>(logitb, wopb, bop, part);
  k_final<<<dim3(8), 256, 0, stream>>>(part, logitb, Wop, bop, y, nllb);
  k_reduce<<<dim3(1), 256, 0, stream>>>(nllb, (float*)d_out);
}

// Round 4
// 5635.049 us; speedup vs baseline: 1.3620x; 1.3620x over previous
//
#include <hip/hip_runtime.h>

#define S_ 50
#define B_ 64
#define T_ 32
#define E_ 512
#define H_ 1024
#define C_ 1024
#define V_ 32000
#define TS_ 31            // T-1 steps
#define NR_ 1984          // TS_*B_ rows
#define NBLK_ 256         // persistent-loop grid size

typedef __attribute__((ext_vector_type(8))) short s8v;   // 8 x bf16 bits
typedef __attribute__((ext_vector_type(4))) float f4v;   // MFMA acc

static __device__ __forceinline__ float b2f(ushort u) {
  unsigned x = ((unsigned)u) << 16; float f; __builtin_memcpy(&f, &x, 4); return f;
}
static __device__ __forceinline__ ushort f2b(float f) {
  unsigned x; __builtin_memcpy(&x, &f, 4);
  x = x + 0x7FFFu + ((x >> 16) & 1u);
  return (ushort)(x >> 16);
}
static __device__ __forceinline__ float sigm(float x) { return 1.f / (1.f + __expf(-x)); }

// A-frag: lane holds row (l&15), k = kb + 8*(l>>4) + j   (16B contiguous load)
static __device__ __forceinline__ s8v ldfrag(const ushort* base, int ld, int row0, int kb, int lane) {
  const ushort* p = base + (size_t)(row0 + (lane & 15)) * ld + (kb + ((lane >> 4) << 3));
  return *reinterpret_cast<const s8v*>(p);
}

// B-frag from swizzled LDS: row r (2KB rows), byte col = kb*2 + (l>>4)*16, XOR (r&7)<<4
static __device__ __forceinline__ s8v ldsfrag(const ushort* base, int r, int kb, int lane) {
  unsigned o = (unsigned)r * 2048u +
               (((unsigned)(kb * 2 + ((lane >> 4) << 4))) ^ ((unsigned)((r & 7) << 4)));
  return *reinterpret_cast<const s8v*>((const char*)base + o);
}

// ---------------- conversions / gathers ----------------

__global__ void k_convert(const float* __restrict__ s, ushort* __restrict__ d, int n) {
  int i = (blockIdx.x * 256 + threadIdx.x) * 4;
  if (i >= n) return;
  float4 v = *reinterpret_cast<const float4*>(s + i);
  ushort4 o; o.x = f2b(v.x); o.y = f2b(v.y); o.z = f2b(v.z); o.w = f2b(v.w);
  *reinterpret_cast<ushort4*>(d + i) = o;
}

// W_c2h (H x C) -> bf16 transposed (C x H)
__global__ void k_convert_T(const float* __restrict__ s, ushort* __restrict__ d) {
  int gid = blockIdx.x * 256 + threadIdx.x;
  int h = gid & 1023, c = gid >> 10;
  d[(size_t)c * 1024 + h] = f2b(s[(size_t)h * 1024 + c]);
}

__global__ void k_gather(const int* __restrict__ y, const float* __restrict__ emb,
                         ushort* __restrict__ xb) {
  int gid = blockIdx.x * 256 + threadIdx.x;
  if (gid >= NR_ * (E_ / 4)) return;
  int i = gid >> 7;
  int c = (gid & 127) << 2;
  int idx = y[i];
  float4 v = make_float4(0.f, 0.f, 0.f, 0.f);
  if (idx != 0) v = *reinterpret_cast<const float4*>(emb + (size_t)idx * E_ + c);
  ushort4 o; o.x = f2b(v.x); o.y = f2b(v.y); o.z = f2b(v.z); o.w = f2b(v.w);
  *reinterpret_cast<ushort4*>(xb + (size_t)i * E_ + c) = o;
}

// ---------------- generic GEMM: out[m,n] = sum_k A[m,k]*B[n,k] (+bias) (opt tanh) ----------------
__global__ void gemm_bt(const ushort* __restrict__ A, const ushort* __restrict__ Bm,
                        const float* __restrict__ bias, float* __restrict__ outF,
                        ushort* __restrict__ outB, int M, int N, int K, int act) {
  int l = threadIdx.x & 63, w = threadIdx.x >> 6;
  int m0 = blockIdx.y * 64 + w * 16;
  int n0 = blockIdx.x * 64;
  f4v acc[4] = {{0.f,0.f,0.f,0.f},{0.f,0.f,0.f,0.f},{0.f,0.f,0.f,0.f},{0.f,0.f,0.f,0.f}};
  for (int kb = 0; kb < K; kb += 32) {
    s8v a = ldfrag(A, K, m0, kb, l);
#pragma unroll
    for (int nt = 0; nt < 4; nt++) {
      s8v b = ldfrag(Bm, K, n0 + nt * 16, kb, l);
      acc[nt] = __builtin_amdgcn_mfma_f32_16x16x32_bf16(a, b, acc[nt], 0, 0, 0);
    }
  }
  int rb = (l >> 4) * 4;
  int col = l & 15;
#pragma unroll
  for (int nt = 0; nt < 4; nt++) {
    int n = n0 + nt * 16 + col;
    float bv = bias ? bias[n] : 0.f;
#pragma unroll
    for (int i = 0; i < 4; i++) {
      int m = m0 + rb + i;
      float v = acc[nt][i] + bv;
      if (act) v = tanhf(v);
      size_t o = (size_t)m * N + n;
      if (outF) outF[o] = v;
      if (outB) outB[o] = f2b(v);
    }
  }
}

// ---------------- persistent sequential loop (cooperative) ----------------

struct LoopP {
  const ushort* whh0b; const ushort* gi0b; const ushort* wh2cb; const ushort* whh1b;
  const ushort* wcombb; const ushort* ctxpb; const ushort* ctxb;
  const float* bhh0; const float* bih1; const float* bhh1; const float* wmlp;
  const float* h0f; const ushort* h0b;
  float* h1f; ushort* h1b; float* hidf; float* gh1f; ushort* zrawb;
  float* H2f; ushort* H2b;
  unsigned* bar;   // [cnt, gen]
};

// grid barrier: release(wbl2) -> arrive -> spin -> acquire(inv). bar memset to 0 per launch.
static __device__ __forceinline__ void gbar(unsigned* bar) {
  __syncthreads();
  if (threadIdx.x == 0) {
    __threadfence();                  // agent release (writeback local L2)
    unsigned* cnt = bar;
    unsigned* gen = bar + 1;
    unsigned g = __hip_atomic_load(gen, __ATOMIC_RELAXED, __HIP_MEMORY_SCOPE_AGENT);
    unsigned v = __hip_atomic_fetch_add(cnt, 1u, __ATOMIC_ACQ_REL, __HIP_MEMORY_SCOPE_AGENT);
    if (v == (unsigned)NBLK_ - 1u) {
      __hip_atomic_store(cnt, 0u, __ATOMIC_RELAXED, __HIP_MEMORY_SCOPE_AGENT);
      __hip_atomic_fetch_add(gen, 1u, __ATOMIC_RELEASE, __HIP_MEMORY_SCOPE_AGENT);
    } else {
      while (__hip_atomic_load(gen, __ATOMIC_RELAXED, __HIP_MEMORY_SCOPE_AGENT) == g)
        __builtin_amdgcn_s_sleep(2);
    }
    __builtin_amdgcn_fence(__ATOMIC_ACQUIRE, "agent");   // invalidate local caches
  }
  __syncthreads();
}

// roles: 0 (blk 0-63)=GRU0/Whh0 ; 1 (64-127)=GRU1/Wcomb ; 2 (128-191)=hid/Wh2c + attn ; 3 (192-255)=gh1/Whh1
__global__ __launch_bounds__(256) void k_loop(LoopP p) {
  __shared__ __align__(16) ushort ldsW[48 * 1024];   // 96KB, 48 rows x 2KB, XOR-swizzled
  __shared__ float hs[C_];
  __shared__ float sc[S_];
  __shared__ float al[S_];

  const int tid = threadIdx.x;
  const int blk = blockIdx.x;
  const int l = tid & 63, w = tid >> 6;
  const int role = blk >> 6;
  const int sub = blk & 63;

  // ---- stage this block's weight slice into swizzled LDS (once) ----
  {
    const ushort* src;
    int nrows;
    if (role == 0)      { src = p.whh0b; nrows = 48; }
    else if (role == 1) { src = p.wcombb; nrows = 48; }
    else if (role == 2) { src = p.wh2cb; nrows = 16; }
    else                { src = p.whh1b; nrows = 48; }
    for (int idx = tid; idx < nrows * 128; idx += 256) {
      int r = idx >> 7, c = idx & 127;
      int grow;
      if (role == 0 || role == 1) grow = (r >> 4) * H_ + sub * 16 + (r & 15);
      else if (role == 2)         grow = sub * 16 + r;
      else                        grow = sub * 48 + r;
      s8v v = *reinterpret_cast<const s8v*>(src + (size_t)grow * 1024 + c * 8);
      unsigned o = (unsigned)r * 2048u + (((unsigned)(c * 16)) ^ ((unsigned)((r & 7) << 4)));
      *reinterpret_cast<s8v*>((char*)ldsW + o) = v;
    }
    __syncthreads();
  }

  const int rr = l & 15;

  for (int t = 0; t < TS_; t++) {
    const float*  hpf = t ? (p.H2f + (size_t)(t - 1) * B_ * H_) : p.h0f;
    const ushort* hpb = t ? (p.H2b + (size_t)(t - 1) * B_ * H_) : p.h0b;
    const ushort* gi0t = p.gi0b + (size_t)t * B_ * 3 * H_;

    // ---- phase A: GRU0 -> h1 (role 0) ----
    if (role == 0) {
      int m0 = w * 16;
      f4v aR = {0.f,0.f,0.f,0.f}, aZ = {0.f,0.f,0.f,0.f}, aN = {0.f,0.f,0.f,0.f};
#pragma unroll 4
      for (int kb = 0; kb < H_; kb += 32) {
        s8v a  = ldfrag(hpb, H_, m0, kb, l);
        s8v bR = ldsfrag(ldsW, rr, kb, l);
        s8v bZ = ldsfrag(ldsW, 16 + rr, kb, l);
        s8v bN = ldsfrag(ldsW, 32 + rr, kb, l);
        aR = __builtin_amdgcn_mfma_f32_16x16x32_bf16(a, bR, aR, 0, 0, 0);
        aZ = __builtin_amdgcn_mfma_f32_16x16x32_bf16(a, bZ, aZ, 0, 0, 0);
        aN = __builtin_amdgcn_mfma_f32_16x16x32_bf16(a, bN, aN, 0, 0, 0);
      }
      int rb = (l >> 4) * 4, c = sub * 16 + (l & 15);
#pragma unroll
      for (int i = 0; i < 4; i++) {
        int m = m0 + rb + i;
        const ushort* gi = gi0t + (size_t)m * (3 * H_);
        float gir = b2f(gi[c]), giz = b2f(gi[H_ + c]), gin = b2f(gi[2 * H_ + c]);
        float ghr = aR[i] + p.bhh0[c], ghz = aZ[i] + p.bhh0[H_ + c], ghn = aN[i] + p.bhh0[2 * H_ + c];
        float r = sigm(gir + ghr);
        float zg = sigm(giz + ghz);
        float nn = tanhf(gin + r * ghn);
        float hp = hpf[(size_t)m * H_ + c];
        float h1 = (1.f - zg) * nn + zg * hp;
        p.h1f[(size_t)m * H_ + c] = h1;
        p.h1b[(size_t)m * H_ + c] = f2b(h1);
      }
    }
    gbar(p.bar);

    // ---- phase B: hid (role 2) | gh1 (role 3) ----
    if (role == 2) {
      int m0 = w * 16;
      f4v acc = {0.f,0.f,0.f,0.f};
#pragma unroll 4
      for (int kb = 0; kb < H_; kb += 32) {
        s8v a = ldfrag(p.h1b, H_, m0, kb, l);
        s8v b = ldsfrag(ldsW, rr, kb, l);
        acc = __builtin_amdgcn_mfma_f32_16x16x32_bf16(a, b, acc, 0, 0, 0);
      }
      int rb = (l >> 4) * 4, c = sub * 16 + (l & 15);
#pragma unroll
      for (int i = 0; i < 4; i++) p.hidf[(size_t)(m0 + rb + i) * C_ + c] = acc[i];
    } else if (role == 3) {
      int m0 = w * 16;
      f4v a0 = {0.f,0.f,0.f,0.f}, a1 = {0.f,0.f,0.f,0.f}, a2 = {0.f,0.f,0.f,0.f};
#pragma unroll 4
      for (int kb = 0; kb < H_; kb += 32) {
        s8v a  = ldfrag(p.h1b, H_, m0, kb, l);
        s8v b0 = ldsfrag(ldsW, rr, kb, l);
        s8v b1 = ldsfrag(ldsW, 16 + rr, kb, l);
        s8v b2 = ldsfrag(ldsW, 32 + rr, kb, l);
        a0 = __builtin_amdgcn_mfma_f32_16x16x32_bf16(a, b0, a0, 0, 0, 0);
        a1 = __builtin_amdgcn_mfma_f32_16x16x32_bf16(a, b1, a1, 0, 0, 0);
        a2 = __builtin_amdgcn_mfma_f32_16x16x32_bf16(a, b2, a2, 0, 0, 0);
      }
      int rb = (l >> 4) * 4, cb = sub * 48 + (l & 15);
#pragma unroll
      for (int i = 0; i < 4; i++) {
        int m = m0 + rb + i;
        p.gh1f[(size_t)m * (3 * H_) + cb]      = a0[i];
        p.gh1f[(size_t)m * (3 * H_) + cb + 16] = a1[i];
        p.gh1f[(size_t)m * (3 * H_) + cb + 32] = a2[i];
      }
    }
    gbar(p.bar);

    // ---- phase C: attention -> z_raw (role 2, b = sub) ----
    if (role == 2) {
      int b = sub;
      for (int c = tid; c < C_; c += 256) hs[c] = p.hidf[(size_t)b * C_ + c];
      __syncthreads();
      for (int s = w; s < S_; s += 4) {
        const ushort* row = p.ctxpb + ((size_t)s * B_ + b) * C_;
        float acc = 0.f;
        for (int c = l; c < C_; c += 64) acc += tanhf(b2f(row[c]) + hs[c]) * p.wmlp[c];
        for (int m = 32; m; m >>= 1) acc += __shfl_xor(acc, m, 64);
        if (l == 0) sc[s] = acc;
      }
      __syncthreads();
      float mx = -1e30f;
      for (int s = 0; s < S_; s++) mx = fmaxf(mx, sc[s]);
      float sm = 0.f;
      for (int s = 0; s < S_; s++) sm += __expf(sc[s] - mx);
      if (tid < S_) al[tid] = __expf(sc[tid] - mx) / sm;
      __syncthreads();
      int c0 = tid * 4;
      float a0 = 0.f, a1 = 0.f, a2 = 0.f, a3 = 0.f;
      for (int s = 0; s < S_; s++) {
        float a = al[s];
        ushort4 cv = *reinterpret_cast<const ushort4*>(p.ctxb + ((size_t)s * B_ + b) * C_ + c0);
        a0 += a * b2f(cv.x); a1 += a * b2f(cv.y); a2 += a * b2f(cv.z); a3 += a * b2f(cv.w);
      }
      ushort4 o; o.x = f2b(a0); o.y = f2b(a1); o.z = f2b(a2); o.w = f2b(a3);
      *reinterpret_cast<ushort4*>(p.zrawb + (size_t)b * C_ + c0) = o;
    }
    gbar(p.bar);

    // ---- phase D: GRU1 -> h2 (=H2[t]) (role 1) ----
    if (role == 1) {
      int m0 = w * 16;
      float* h2f = p.H2f + (size_t)t * B_ * H_;
      ushort* h2b = p.H2b + (size_t)t * B_ * H_;
      f4v aR = {0.f,0.f,0.f,0.f}, aZ = {0.f,0.f,0.f,0.f}, aN = {0.f,0.f,0.f,0.f};
#pragma unroll 4
      for (int kb = 0; kb < C_; kb += 32) {
        s8v a  = ldfrag(p.zrawb, C_, m0, kb, l);
        s8v bR = ldsfrag(ldsW, rr, kb, l);
        s8v bZ = ldsfrag(ldsW, 16 + rr, kb, l);
        s8v bN = ldsfrag(ldsW, 32 + rr, kb, l);
        aR = __builtin_amdgcn_mfma_f32_16x16x32_bf16(a, bR, aR, 0, 0, 0);
        aZ = __builtin_amdgcn_mfma_f32_16x16x32_bf16(a, bZ, aZ, 0, 0, 0);
        aN = __builtin_amdgcn_mfma_f32_16x16x32_bf16(a, bN, aN, 0, 0, 0);
      }
      int rb = (l >> 4) * 4, c = sub * 16 + (l & 15);
#pragma unroll
      for (int i = 0; i < 4; i++) {
        int m = m0 + rb + i;
        float gir = aR[i] + p.bih1[c], giz = aZ[i] + p.bih1[H_ + c], gin = aN[i] + p.bih1[2 * H_ + c];
        const float* gh = p.gh1f + (size_t)m * (3 * H_);
        float ghr = gh[c] + p.bhh1[c], ghz = gh[H_ + c] + p.bhh1[H_ + c], ghn = gh[2 * H_ + c] + p.bhh1[2 * H_ + c];
        float r = sigm(gir + ghr);
        float zg = sigm(giz + ghz);
        float nn = tanhf(gin + r * ghn);
        float h1 = p.h1f[(size_t)m * H_ + c];
        float h2 = (1.f - zg) * nn + zg * h1;
        h2f[(size_t)m * H_ + c] = h2;
        h2b[(size_t)m * H_ + c] = f2b(h2);
      }
    }
    gbar(p.bar);
  }
}

// ---------------- epilogue: streaming LSE over vocab ----------------
#define LSE_NCH 40
#define LSE_TILES 50    // 16-col tiles per chunk (40*50*16 = 32000)

__global__ __launch_bounds__(512) void k_lse2(const ushort* __restrict__ logitb,
                                              const ushort* __restrict__ wopb,
                                              const float* __restrict__ bop,
                                              float* __restrict__ part) {
  __shared__ ushort Bs[2][16 * E_];   // 2 x 16KB (16 rows x 1024B)
  int tid = threadIdx.x, l = tid & 63, w = tid >> 6;
  int r0 = blockIdx.y * 128 + w * 16;
  int c0 = blockIdx.x * (LSE_TILES * 16);
  int arow = r0 + (l & 15);
  bool aok = arow < NR_;

  s8v afr[16];
#pragma unroll
  for (int kk = 0; kk < 16; kk++) {
    s8v z = {0,0,0,0,0,0,0,0};
    afr[kk] = aok ? *reinterpret_cast<const s8v*>(logitb + (size_t)arow * E_ + kk * 32 + ((l >> 4) << 3)) : z;
  }

  const int srow = tid >> 5;
  const int scb = (tid & 31) * 32;
  const unsigned sxr = (unsigned)((srow & 7) << 4);
  char* sdst0 = (char*)&Bs[0][0] + srow * 1024;
  char* sdst1 = (char*)&Bs[1][0] + srow * 1024;

  const int brow = l & 15;
  const unsigned lanep = (unsigned)((l >> 4) << 4);
  const unsigned xorv = (unsigned)((brow & 7) << 4);
  const char* bbase0 = (const char*)&Bs[0][0] + brow * 1024;
  const char* bbase1 = (const char*)&Bs[1][0] + brow * 1024;

  f4v mr = {-1e30f, -1e30f, -1e30f, -1e30f};
  f4v sr = {0.f, 0.f, 0.f, 0.f};

  {
    const char* src = (const char*)(wopb + (size_t)(c0 + srow) * E_) + scb;
    s8v g0 = *reinterpret_cast<const s8v*>(src);
    s8v g1 = *reinterpret_cast<const s8v*>(src + 16);
    *reinterpret_cast<s8v*>(sdst0 + ((unsigned)scb ^ sxr)) = g0;
    *reinterpret_cast<s8v*>(sdst0 + (((unsigned)scb + 16u) ^ sxr)) = g1;
  }
  __syncthreads();

  for (int tt = 0; tt < LSE_TILES; tt++) {
    int cur = tt & 1;
    bool more = (tt + 1) < LSE_TILES;
    s8v g0, g1;
    if (more) {
      const char* src = (const char*)(wopb + (size_t)(c0 + (tt + 1) * 16 + srow) * E_) + scb;
      g0 = *reinterpret_cast<const s8v*>(src);
      g1 = *reinterpret_cast<const s8v*>(src + 16);
    }
    const char* bbase = cur ? bbase1 : bbase0;
    f4v acc = {0.f, 0.f, 0.f, 0.f};
#pragma unroll
    for (int kk = 0; kk < 16; kk++) {
      unsigned off = ((unsigned)(kk * 64) + lanep) ^ xorv;
      s8v b = *reinterpret_cast<const s8v*>(bbase + off);
      acc = __builtin_amdgcn_mfma_f32_16x16x32_bf16(afr[kk], b, acc, 0, 0, 0);
    }
    float bv = bop[c0 + tt * 16 + (l & 15)];
#pragma unroll
    for (int i = 0; i < 4; i++) {
      float v = acc[i] + bv;
      if (v <= mr[i]) {
        sr[i] += __expf(v - mr[i]);
      } else {
        sr[i] = sr[i] * __expf(mr[i] - v) + 1.f;
        mr[i] = v;
      }
    }
    if (more) {
      char* sdst = cur ? sdst0 : sdst1;
      *reinterpret_cast<s8v*>(sdst + ((unsigned)scb ^ sxr)) = g0;
      *reinterpret_cast<s8v*>(sdst + (((unsigned)scb + 16u) ^ sxr)) = g1;
      __syncthreads();
    }
  }

  for (int sh = 1; sh < 16; sh <<= 1) {
#pragma unroll
    for (int i = 0; i < 4; i++) {
      float om = __shfl_xor(mr[i], sh, 64);
      float os = __shfl_xor(sr[i], sh, 64);
      float mn = fmaxf(mr[i], om);
      sr[i] = sr[i] * __expf(mr[i] - mn) + os * __expf(om - mn);
      mr[i] = mn;
    }
  }
  if ((l & 15) == 0) {
#pragma unroll
    for (int i = 0; i < 4; i++) {
      int row = r0 + (l >> 4) * 4 + i;
      if (row < NR_) {
        size_t o = ((size_t)row * LSE_NCH + blockIdx.x) * 2;
        part[o] = mr[i];
        part[o + 1] = sr[i];
      }
    }
  }
}

__global__ void k_final(const float* __restrict__ part, const ushort* __restrict__ logitb,
                        const float* __restrict__ Wop, const float* __restrict__ bop,
                        const int* __restrict__ y, float* __restrict__ nll) {
  int i = blockIdx.x * 256 + threadIdx.x;
  if (i >= NR_) return;
  float m = -1e30f;
  for (int c = 0; c < LSE_NCH; c++) m = fmaxf(m, part[((size_t)i * LSE_NCH + c) * 2]);
  float s = 0.f;
  for (int c = 0; c < LSE_NCH; c++) {
    size_t o = ((size_t)i * LSE_NCH + c) * 2;
    s += part[o + 1] * __expf(part[o] - m);
  }
  float lse = m + logf(s);
  int tgt = y[i + B_];
  float v = 0.f;
  if (tgt != 0) {
    const ushort* lr = logitb + (size_t)i * E_;
    const float* wr = Wop + (size_t)tgt * E_;
    float dot = 0.f;
    for (int k = 0; k < E_; k++) dot += b2f(lr[k]) * wr[k];
    dot += bop[tgt];
    v = lse - dot;
  }
  nll[i] = v;
}

__global__ void k_reduce(const float* __restrict__ nll, float* __restrict__ out) {
  __shared__ float sh[256];
  float a = 0.f;
  for (int i = threadIdx.x; i < NR_; i += 256) a += nll[i];
  sh[threadIdx.x] = a;
  __syncthreads();
  for (int s = 128; s; s >>= 1) {
    if (threadIdx.x < s) sh[threadIdx.x] += sh[threadIdx.x + s];
    __syncthreads();
  }
  if (threadIdx.x == 0) out[0] = sh[0];
}

// ---------------- host ----------------

extern "C" void kernel_launch(void* const* d_in, const int* in_sizes, int n_in,
                              void* d_out, int out_size, void* d_ws, size_t ws_size,
                              hipStream_t stream) {
  const float* ctx  = (const float*)d_in[0];
  const int*   y    = (const int*)d_in[1];
  const float* emb  = (const float*)d_in[2];
  const float* Wih0 = (const float*)d_in[3];
  const float* Whh0 = (const float*)d_in[4];
  const float* bih0 = (const float*)d_in[5];
  const float* bhh0 = (const float*)d_in[6];
  const float* Wih1 = (const float*)d_in[7];
  const float* Whh1 = (const float*)d_in[8];
  const float* bih1 = (const float*)d_in[9];
  const float* bhh1 = (const float*)d_in[10];
  const float* Wc2c = (const float*)d_in[11];
  const float* Wh2c = (const float*)d_in[12];
  const float* wmlp = (const float*)d_in[13];
  const float* Wc2h = (const float*)d_in[14];
  const float* Who  = (const float*)d_in[15];
  const float* bho  = (const float*)d_in[16];
  const float* Wop  = (const float*)d_in[17];
  const float* bop  = (const float*)d_in[18];

  char* ws = (char*)d_ws;
  size_t off = 0;
  auto alloc = [&](size_t bytes) { void* p = ws + off; off += (bytes + 255) & ~size_t(255); return p; };

  ushort* ctxb   = (ushort*)alloc((size_t)S_ * B_ * C_ * 2);
  ushort* wih0b  = (ushort*)alloc((size_t)3 * H_ * E_ * 2);
  ushort* whh0b  = (ushort*)alloc((size_t)3 * H_ * H_ * 2);
  ushort* wh2cb  = (ushort*)alloc((size_t)C_ * H_ * 2);
  ushort* wc2hT  = (ushort*)alloc((size_t)C_ * H_ * 2);
  ushort* wih1b  = (ushort*)alloc((size_t)3 * H_ * H_ * 2);
  ushort* whh1b  = (ushort*)alloc((size_t)3 * H_ * H_ * 2);
  ushort* whob   = (ushort*)alloc((size_t)E_ * H_ * 2);
  ushort* wopb   = (ushort*)alloc((size_t)V_ * E_ * 2);
  ushort* wc2cb  = (ushort*)alloc((size_t)C_ * C_ * 2);
  ushort* wcombb = (ushort*)alloc((size_t)3 * H_ * C_ * 2);
  ushort* xb     = (ushort*)alloc((size_t)NR_ * E_ * 2);
  ushort* gi0b   = (ushort*)alloc((size_t)NR_ * 3 * H_ * 2);
  ushort* ctxpb  = (ushort*)alloc((size_t)S_ * B_ * C_ * 2);
  float*  H2f    = (float*)alloc((size_t)TS_ * B_ * H_ * 4);
  ushort* H2b    = (ushort*)alloc((size_t)TS_ * B_ * H_ * 2);
  float*  h0f    = (float*)alloc((size_t)B_ * H_ * 4);
  ushort* h0b    = (ushort*)alloc((size_t)B_ * H_ * 2);
  float*  h1f    = (float*)alloc((size_t)B_ * H_ * 4);
  ushort* h1b    = (ushort*)alloc((size_t)B_ * H_ * 2);
  float*  hidf   = (float*)alloc((size_t)B_ * C_ * 4);
  float*  gh1f   = (float*)alloc((size_t)B_ * 3 * H_ * 4);
  ushort* zrawb  = (ushort*)alloc((size_t)B_ * C_ * 2);
  ushort* logitb = (ushort*)alloc((size_t)NR_ * E_ * 2);
  float*  part   = (float*)alloc((size_t)2048 * LSE_NCH * 2 * 4);
  float*  nllb   = (float*)alloc((size_t)2048 * 4);
  unsigned* bar  = (unsigned*)alloc(256);
  (void)ws_size; (void)in_sizes; (void)n_in; (void)out_size;

  (void)hipMemsetAsync(h0f, 0, (size_t)B_ * H_ * 4, stream);
  (void)hipMemsetAsync(h0b, 0, (size_t)B_ * H_ * 2, stream);
  (void)hipMemsetAsync(bar, 0, 256, stream);

  auto cgrid = [](int n) { return dim3((unsigned)((n / 4 + 255) / 256)); };
  k_convert<<<cgrid(S_ * B_ * C_), 256, 0, stream>>>(ctx, ctxb, S_ * B_ * C_);
  k_convert<<<cgrid(3 * H_ * E_), 256, 0, stream>>>(Wih0, wih0b, 3 * H_ * E_);
  k_convert<<<cgrid(3 * H_ * H_), 256, 0, stream>>>(Whh0, whh0b, 3 * H_ * H_);
  k_convert<<<cgrid(C_ * H_), 256, 0, stream>>>(Wh2c, wh2cb, C_ * H_);
  k_convert<<<cgrid(3 * H_ * H_), 256, 0, stream>>>(Wih1, wih1b, 3 * H_ * H_);
  k_convert<<<cgrid(3 * H_ * H_), 256, 0, stream>>>(Whh1, whh1b, 3 * H_ * H_);
  k_convert<<<cgrid(E_ * H_), 256, 0, stream>>>(Who, whob, E_ * H_);
  k_convert<<<cgrid(V_ * E_), 256, 0, stream>>>(Wop, wopb, V_ * E_);
  k_convert<<<cgrid(C_ * C_), 256, 0, stream>>>(Wc2c, wc2cb, C_ * C_);
  k_convert_T<<<dim3(4096), 256, 0, stream>>>(Wc2h, wc2hT);

  k_gather<<<dim3((NR_ * (E_ / 4) + 255) / 256), 256, 0, stream>>>(y, emb, xb);

  gemm_bt<<<dim3(3 * H_ / 64, NR_ / 64), 256, 0, stream>>>(xb, wih0b, bih0, nullptr, gi0b,
                                                           NR_, 3 * H_, E_, 0);
  gemm_bt<<<dim3(C_ / 64, S_ * B_ / 64), 256, 0, stream>>>(ctxb, wc2cb, nullptr, nullptr, ctxpb,
                                                           S_ * B_, C_, C_, 0);
  gemm_bt<<<dim3(C_ / 64, 3 * H_ / 64), 256, 0, stream>>>(wih1b, wc2hT, nullptr, nullptr, wcombb,
                                                          3 * H_, C_, H_, 0);

  LoopP p;
  p.whh0b = whh0b; p.gi0b = gi0b; p.wh2cb = wh2cb; p.whh1b = whh1b;
  p.wcombb = wcombb; p.ctxpb = ctxpb; p.ctxb = ctxb;
  p.bhh0 = bhh0; p.bih1 = bih1; p.bhh1 = bhh1; p.wmlp = wmlp;
  p.h0f = h0f; p.h0b = h0b;
  p.h1f = h1f; p.h1b = h1b; p.hidf = hidf; p.gh1f = gh1f; p.zrawb = zrawb;
  p.H2f = H2f; p.H2b = H2b; p.bar = bar;
  void* args[] = { (void*)&p };
  (void)hipLaunchCooperativeKernel(k_loop, dim3(NBLK_), dim3(256), args, 0, stream);

  gemm_bt<<<dim3(E_ / 64, NR_ / 64), 256, 0, stream>>>(H2b, whob, bho, nullptr, logitb,
                                                       NR_, E_, H_, 1);
  k_lse2<<<dim3(LSE_NCH, 16), 512, 0, stream>>>(logitb, wopb, bop, part);
  k_final<<<dim3(8), 256, 0, stream>>>(part, logitb, Wop, bop, y, nllb);
  k_reduce<<<dim3(1), 256, 0, stream>>>(nllb, (float*)d_out);
}

// Round 5
// 4145.670 us; speedup vs baseline: 1.8513x; 1.3593x over previous
//
#include <hip/hip_runtime.h>

#define S_ 50
#define B_ 64
#define T_ 32
#define E_ 512
#define H_ 1024
#define C_ 1024
#define V_ 32000
#define TS_ 31            // T-1 steps
#define NR_ 1984          // TS_*B_ rows
#define NBLK_ 256         // persistent-loop grid size

typedef __attribute__((ext_vector_type(8))) short s8v;   // 8 x bf16 bits
typedef __attribute__((ext_vector_type(4))) float f4v;   // MFMA acc

static __device__ __forceinline__ float b2f(ushort u) {
  unsigned x = ((unsigned)u) << 16; float f; __builtin_memcpy(&f, &x, 4); return f;
}
static __device__ __forceinline__ ushort f2b(float f) {
  unsigned x; __builtin_memcpy(&x, &f, 4);
  x = x + 0x7FFFu + ((x >> 16) & 1u);
  return (ushort)(x >> 16);
}
static __device__ __forceinline__ float sigm(float x) { return 1.f / (1.f + __expf(-x)); }

// ---- coherence-point (sc0 sc1) access helpers: RELAXED AGENT atomics ----
static __device__ __forceinline__ void st_f32(float* p, float v) {
  __hip_atomic_store(p, v, __ATOMIC_RELAXED, __HIP_MEMORY_SCOPE_AGENT);
}
static __device__ __forceinline__ float ld_f32(const float* p) {
  return __hip_atomic_load(p, __ATOMIC_RELAXED, __HIP_MEMORY_SCOPE_AGENT);
}
static __device__ __forceinline__ void st_u64(void* p, unsigned long long v) {
  __hip_atomic_store((unsigned long long*)p, v, __ATOMIC_RELAXED, __HIP_MEMORY_SCOPE_AGENT);
}
static __device__ __forceinline__ unsigned long long ld_u64(const void* p) {
  return __hip_atomic_load((const unsigned long long*)p, __ATOMIC_RELAXED, __HIP_MEMORY_SCOPE_AGENT);
}

// A-frag: lane holds row (l&15), k = kb + 8*(l>>4) + j   (16B contiguous load)
static __device__ __forceinline__ s8v ldfrag(const ushort* base, int ld, int row0, int kb, int lane) {
  const ushort* p = base + (size_t)(row0 + (lane & 15)) * ld + (kb + ((lane >> 4) << 3));
  return *reinterpret_cast<const s8v*>(p);
}
// coherent variant (cross-block activations): 2 x u64 relaxed-agent loads
static __device__ __forceinline__ s8v ldfrag_c(const ushort* base, int ld, int row0, int kb, int lane) {
  const ushort* p = base + (size_t)(row0 + (lane & 15)) * ld + (kb + ((lane >> 4) << 3));
  union { unsigned long long q[2]; s8v v; } u;
  u.q[0] = ld_u64(p);
  u.q[1] = ld_u64(p + 4);
  return u.v;
}

// B-frag from swizzled LDS: row r (2KB rows), byte col = kb*2 + (l>>4)*16, XOR (r&7)<<4
static __device__ __forceinline__ s8v ldsfrag(const ushort* base, int r, int kb, int lane) {
  unsigned o = (unsigned)r * 2048u +
               (((unsigned)(kb * 2 + ((lane >> 4) << 4))) ^ ((unsigned)((r & 7) << 4)));
  return *reinterpret_cast<const s8v*>((const char*)base + o);
}

// ---------------- conversions / gathers ----------------

__global__ void k_convert(const float* __restrict__ s, ushort* __restrict__ d, int n) {
  int i = (blockIdx.x * 256 + threadIdx.x) * 4;
  if (i >= n) return;
  float4 v = *reinterpret_cast<const float4*>(s + i);
  ushort4 o; o.x = f2b(v.x); o.y = f2b(v.y); o.z = f2b(v.z); o.w = f2b(v.w);
  *reinterpret_cast<ushort4*>(d + i) = o;
}

// W_c2h (H x C) -> bf16 transposed (C x H)
__global__ void k_convert_T(const float* __restrict__ s, ushort* __restrict__ d) {
  int gid = blockIdx.x * 256 + threadIdx.x;
  int h = gid & 1023, c = gid >> 10;
  d[(size_t)c * 1024 + h] = f2b(s[(size_t)h * 1024 + c]);
}

__global__ void k_gather(const int* __restrict__ y, const float* __restrict__ emb,
                         ushort* __restrict__ xb) {
  int gid = blockIdx.x * 256 + threadIdx.x;
  if (gid >= NR_ * (E_ / 4)) return;
  int i = gid >> 7;
  int c = (gid & 127) << 2;
  int idx = y[i];
  float4 v = make_float4(0.f, 0.f, 0.f, 0.f);
  if (idx != 0) v = *reinterpret_cast<const float4*>(emb + (size_t)idx * E_ + c);
  ushort4 o; o.x = f2b(v.x); o.y = f2b(v.y); o.z = f2b(v.z); o.w = f2b(v.w);
  *reinterpret_cast<ushort4*>(xb + (size_t)i * E_ + c) = o;
}

// ---------------- generic GEMM: out[m,n] = sum_k A[m,k]*B[n,k] (+bias) (opt tanh) ----------------
__global__ void gemm_bt(const ushort* __restrict__ A, const ushort* __restrict__ Bm,
                        const float* __restrict__ bias, float* __restrict__ outF,
                        ushort* __restrict__ outB, int M, int N, int K, int act) {
  int l = threadIdx.x & 63, w = threadIdx.x >> 6;
  int m0 = blockIdx.y * 64 + w * 16;
  int n0 = blockIdx.x * 64;
  f4v acc[4] = {{0.f,0.f,0.f,0.f},{0.f,0.f,0.f,0.f},{0.f,0.f,0.f,0.f},{0.f,0.f,0.f,0.f}};
  for (int kb = 0; kb < K; kb += 32) {
    s8v a = ldfrag(A, K, m0, kb, l);
#pragma unroll
    for (int nt = 0; nt < 4; nt++) {
      s8v b = ldfrag(Bm, K, n0 + nt * 16, kb, l);
      acc[nt] = __builtin_amdgcn_mfma_f32_16x16x32_bf16(a, b, acc[nt], 0, 0, 0);
    }
  }
  int rb = (l >> 4) * 4;
  int col = l & 15;
#pragma unroll
  for (int nt = 0; nt < 4; nt++) {
    int n = n0 + nt * 16 + col;
    float bv = bias ? bias[n] : 0.f;
#pragma unroll
    for (int i = 0; i < 4; i++) {
      int m = m0 + rb + i;
      float v = acc[nt][i] + bv;
      if (act) v = tanhf(v);
      size_t o = (size_t)m * N + n;
      if (outF) outF[o] = v;
      if (outB) outB[o] = f2b(v);
    }
  }
}

// ---------------- persistent sequential loop (cooperative) ----------------

struct LoopP {
  const ushort* whh0b; const ushort* gi0b; const ushort* wh2cb; const ushort* whh1b;
  const ushort* wcombb; const ushort* ctxpb; const ushort* ctxb;
  const float* bhh0; const float* bih1; const float* bhh1; const float* wmlp;
  const float* h0f; const ushort* h0b;
  float* h1f; ushort* h1b; float* hidf; float* gh1f; ushort* zrawb;
  float* H2f; ushort* H2b;
  unsigned* bar;   // monotonic counter, memset 0 per launch
};

// fence-free monotonic grid barrier. __syncthreads drains vmcnt (sc1 stores are
// then at the coherence point); relaxed agent add + spin; no wbl2/inv.
static __device__ __forceinline__ void gbar(unsigned* cnt, unsigned target) {
  __syncthreads();
  if (threadIdx.x == 0) {
    __hip_atomic_fetch_add(cnt, 1u, __ATOMIC_RELAXED, __HIP_MEMORY_SCOPE_AGENT);
    while (__hip_atomic_load(cnt, __ATOMIC_RELAXED, __HIP_MEMORY_SCOPE_AGENT) < target)
      __builtin_amdgcn_s_sleep(1);
  }
  __syncthreads();
}

// roles: 0 (blk 0-63)=GRU0/Whh0 ; 1 (64-127)=GRU1/Wcomb ; 2 (128-191)=hid/Wh2c + attn ; 3 (192-255)=gh1/Whh1
__global__ __launch_bounds__(256) void k_loop(LoopP p) {
  __shared__ __align__(16) ushort ldsW[48 * 1024];   // 96KB, 48 rows x 2KB, XOR-swizzled
  __shared__ float hs[C_];
  __shared__ float sc[S_];
  __shared__ float al[S_];
  __shared__ __align__(8) ushort stile[64 * 16];     // bf16 epilogue re-layout tile

  const int tid = threadIdx.x;
  const int blk = blockIdx.x;
  const int l = tid & 63, w = tid >> 6;
  const int role = blk >> 6;
  const int sub = blk & 63;

  // ---- stage this block's weight slice into swizzled LDS (once) ----
  {
    const ushort* src;
    int nrows;
    if (role == 0)      { src = p.whh0b; nrows = 48; }
    else if (role == 1) { src = p.wcombb; nrows = 48; }
    else if (role == 2) { src = p.wh2cb; nrows = 16; }
    else                { src = p.whh1b; nrows = 48; }
    for (int idx = tid; idx < nrows * 128; idx += 256) {
      int r = idx >> 7, c = idx & 127;
      int grow;
      if (role == 0 || role == 1) grow = (r >> 4) * H_ + sub * 16 + (r & 15);
      else if (role == 2)         grow = sub * 16 + r;
      else                        grow = sub * 48 + r;
      s8v v = *reinterpret_cast<const s8v*>(src + (size_t)grow * 1024 + c * 8);
      unsigned o = (unsigned)r * 2048u + (((unsigned)(c * 16)) ^ ((unsigned)((r & 7) << 4)));
      *reinterpret_cast<s8v*>((char*)ldsW + o) = v;
    }
    __syncthreads();
  }

  const int rr = l & 15;
  unsigned bt = NBLK_;

  for (int t = 0; t < TS_; t++) {
    const float*  hpf = t ? (p.H2f + (size_t)(t - 1) * B_ * H_) : p.h0f;
    const ushort* hpb = t ? (p.H2b + (size_t)(t - 1) * B_ * H_) : p.h0b;
    const ushort* gi0t = p.gi0b + (size_t)t * B_ * 3 * H_;

    // ---- phase A: GRU0 -> h1 (role 0) ----
    if (role == 0) {
      int m0 = w * 16;
      f4v aR = {0.f,0.f,0.f,0.f}, aZ = {0.f,0.f,0.f,0.f}, aN = {0.f,0.f,0.f,0.f};
#pragma unroll 4
      for (int kb = 0; kb < H_; kb += 32) {
        s8v a  = ldfrag_c(hpb, H_, m0, kb, l);
        s8v bR = ldsfrag(ldsW, rr, kb, l);
        s8v bZ = ldsfrag(ldsW, 16 + rr, kb, l);
        s8v bN = ldsfrag(ldsW, 32 + rr, kb, l);
        aR = __builtin_amdgcn_mfma_f32_16x16x32_bf16(a, bR, aR, 0, 0, 0);
        aZ = __builtin_amdgcn_mfma_f32_16x16x32_bf16(a, bZ, aZ, 0, 0, 0);
        aN = __builtin_amdgcn_mfma_f32_16x16x32_bf16(a, bN, aN, 0, 0, 0);
      }
      int rb = (l >> 4) * 4, c15 = l & 15, c = sub * 16 + c15;
#pragma unroll
      for (int i = 0; i < 4; i++) {
        int m = m0 + rb + i;
        const ushort* gi = gi0t + (size_t)m * (3 * H_);
        float gir = b2f(gi[c]), giz = b2f(gi[H_ + c]), gin = b2f(gi[2 * H_ + c]);
        float ghr = aR[i] + p.bhh0[c], ghz = aZ[i] + p.bhh0[H_ + c], ghn = aN[i] + p.bhh0[2 * H_ + c];
        float r = sigm(gir + ghr);
        float zg = sigm(giz + ghz);
        float nn = tanhf(gin + r * ghn);
        float hp = ld_f32(&hpf[(size_t)m * H_ + c]);
        float h1 = (1.f - zg) * nn + zg * hp;
        st_f32(&p.h1f[(size_t)m * H_ + c], h1);
        stile[m * 16 + c15] = f2b(h1);
      }
      __syncthreads();
      {
        int row = tid >> 2, ch = tid & 3;
        unsigned long long v = *reinterpret_cast<unsigned long long*>(&stile[row * 16 + ch * 4]);
        st_u64(&p.h1b[(size_t)row * H_ + sub * 16 + ch * 4], v);
      }
    }
    gbar(p.bar, bt); bt += NBLK_;

    // ---- phase B: hid (role 2) | gh1 (role 3) ----
    if (role == 2) {
      int m0 = w * 16;
      f4v acc = {0.f,0.f,0.f,0.f};
#pragma unroll 4
      for (int kb = 0; kb < H_; kb += 32) {
        s8v a = ldfrag_c(p.h1b, H_, m0, kb, l);
        s8v b = ldsfrag(ldsW, rr, kb, l);
        acc = __builtin_amdgcn_mfma_f32_16x16x32_bf16(a, b, acc, 0, 0, 0);
      }
      int rb = (l >> 4) * 4, c = sub * 16 + (l & 15);
#pragma unroll
      for (int i = 0; i < 4; i++) st_f32(&p.hidf[(size_t)(m0 + rb + i) * C_ + c], acc[i]);
    } else if (role == 3) {
      int m0 = w * 16;
      f4v a0 = {0.f,0.f,0.f,0.f}, a1 = {0.f,0.f,0.f,0.f}, a2 = {0.f,0.f,0.f,0.f};
#pragma unroll 4
      for (int kb = 0; kb < H_; kb += 32) {
        s8v a  = ldfrag_c(p.h1b, H_, m0, kb, l);
        s8v b0 = ldsfrag(ldsW, rr, kb, l);
        s8v b1 = ldsfrag(ldsW, 16 + rr, kb, l);
        s8v b2 = ldsfrag(ldsW, 32 + rr, kb, l);
        a0 = __builtin_amdgcn_mfma_f32_16x16x32_bf16(a, b0, a0, 0, 0, 0);
        a1 = __builtin_amdgcn_mfma_f32_16x16x32_bf16(a, b1, a1, 0, 0, 0);
        a2 = __builtin_amdgcn_mfma_f32_16x16x32_bf16(a, b2, a2, 0, 0, 0);
      }
      int rb = (l >> 4) * 4, cb = sub * 48 + (l & 15);
#pragma unroll
      for (int i = 0; i < 4; i++) {
        int m = m0 + rb + i;
        st_f32(&p.gh1f[(size_t)m * (3 * H_) + cb],      a0[i]);
        st_f32(&p.gh1f[(size_t)m * (3 * H_) + cb + 16], a1[i]);
        st_f32(&p.gh1f[(size_t)m * (3 * H_) + cb + 32], a2[i]);
      }
    }
    gbar(p.bar, bt); bt += NBLK_;

    // ---- phase C: attention -> z_raw (role 2, b = sub) ----
    if (role == 2) {
      int b = sub;
      for (int c = tid; c < C_; c += 256) hs[c] = ld_f32(&p.hidf[(size_t)b * C_ + c]);
      __syncthreads();
      for (int s = w; s < S_; s += 4) {
        const ushort* row = p.ctxpb + ((size_t)s * B_ + b) * C_;
        float acc = 0.f;
        for (int c = l; c < C_; c += 64) acc += tanhf(b2f(row[c]) + hs[c]) * p.wmlp[c];
        for (int m = 32; m; m >>= 1) acc += __shfl_xor(acc, m, 64);
        if (l == 0) sc[s] = acc;
      }
      __syncthreads();
      float mx = -1e30f;
      for (int s = 0; s < S_; s++) mx = fmaxf(mx, sc[s]);
      float sm = 0.f;
      for (int s = 0; s < S_; s++) sm += __expf(sc[s] - mx);
      if (tid < S_) al[tid] = __expf(sc[tid] - mx) / sm;
      __syncthreads();
      int c0 = tid * 4;
      float a0 = 0.f, a1 = 0.f, a2 = 0.f, a3 = 0.f;
      for (int s = 0; s < S_; s++) {
        float a = al[s];
        ushort4 cv = *reinterpret_cast<const ushort4*>(p.ctxb + ((size_t)s * B_ + b) * C_ + c0);
        a0 += a * b2f(cv.x); a1 += a * b2f(cv.y); a2 += a * b2f(cv.z); a3 += a * b2f(cv.w);
      }
      ushort4 o; o.x = f2b(a0); o.y = f2b(a1); o.z = f2b(a2); o.w = f2b(a3);
      unsigned long long pk; __builtin_memcpy(&pk, &o, 8);
      st_u64(p.zrawb + (size_t)b * C_ + c0, pk);
    }
    gbar(p.bar, bt); bt += NBLK_;

    // ---- phase D: GRU1 -> h2 (=H2[t]) (role 1) ----
    if (role == 1) {
      int m0 = w * 16;
      float* h2f = p.H2f + (size_t)t * B_ * H_;
      ushort* h2b = p.H2b + (size_t)t * B_ * H_;
      f4v aR = {0.f,0.f,0.f,0.f}, aZ = {0.f,0.f,0.f,0.f}, aN = {0.f,0.f,0.f,0.f};
#pragma unroll 4
      for (int kb = 0; kb < C_; kb += 32) {
        s8v a  = ldfrag_c(p.zrawb, C_, m0, kb, l);
        s8v bR = ldsfrag(ldsW, rr, kb, l);
        s8v bZ = ldsfrag(ldsW, 16 + rr, kb, l);
        s8v bN = ldsfrag(ldsW, 32 + rr, kb, l);
        aR = __builtin_amdgcn_mfma_f32_16x16x32_bf16(a, bR, aR, 0, 0, 0);
        aZ = __builtin_amdgcn_mfma_f32_16x16x32_bf16(a, bZ, aZ, 0, 0, 0);
        aN = __builtin_amdgcn_mfma_f32_16x16x32_bf16(a, bN, aN, 0, 0, 0);
      }
      int rb = (l >> 4) * 4, c15 = l & 15, c = sub * 16 + c15;
#pragma unroll
      for (int i = 0; i < 4; i++) {
        int m = m0 + rb + i;
        float gir = aR[i] + p.bih1[c], giz = aZ[i] + p.bih1[H_ + c], gin = aN[i] + p.bih1[2 * H_ + c];
        float ghr = ld_f32(&p.gh1f[(size_t)m * (3 * H_) + c])           + p.bhh1[c];
        float ghz = ld_f32(&p.gh1f[(size_t)m * (3 * H_) + H_ + c])      + p.bhh1[H_ + c];
        float ghn = ld_f32(&p.gh1f[(size_t)m * (3 * H_) + 2 * H_ + c])  + p.bhh1[2 * H_ + c];
        float r = sigm(gir + ghr);
        float zg = sigm(giz + ghz);
        float nn = tanhf(gin + r * ghn);
        float h1 = ld_f32(&p.h1f[(size_t)m * H_ + c]);
        float h2 = (1.f - zg) * nn + zg * h1;
        st_f32(&h2f[(size_t)m * H_ + c], h2);
        stile[m * 16 + c15] = f2b(h2);
      }
      __syncthreads();
      {
        int row = tid >> 2, ch = tid & 3;
        unsigned long long v = *reinterpret_cast<unsigned long long*>(&stile[row * 16 + ch * 4]);
        st_u64(&h2b[(size_t)row * H_ + sub * 16 + ch * 4], v);
      }
    }
    gbar(p.bar, bt); bt += NBLK_;
  }
}

// ---------------- epilogue: streaming LSE over vocab ----------------
#define LSE_NCH 40
#define LSE_TILES 50    // 16-col tiles per chunk (40*50*16 = 32000)

__global__ __launch_bounds__(512) void k_lse2(const ushort* __restrict__ logitb,
                                              const ushort* __restrict__ wopb,
                                              const float* __restrict__ bop,
                                              float* __restrict__ part) {
  __shared__ ushort Bs[2][16 * E_];   // 2 x 16KB (16 rows x 1024B)
  int tid = threadIdx.x, l = tid & 63, w = tid >> 6;
  int r0 = blockIdx.y * 128 + w * 16;
  int c0 = blockIdx.x * (LSE_TILES * 16);
  int arow = r0 + (l & 15);
  bool aok = arow < NR_;

  s8v afr[16];
#pragma unroll
  for (int kk = 0; kk < 16; kk++) {
    s8v z = {0,0,0,0,0,0,0,0};
    afr[kk] = aok ? *reinterpret_cast<const s8v*>(logitb + (size_t)arow * E_ + kk * 32 + ((l >> 4) << 3)) : z;
  }

  const int srow = tid >> 5;
  const int scb = (tid & 31) * 32;
  const unsigned sxr = (unsigned)((srow & 7) << 4);
  char* sdst0 = (char*)&Bs[0][0] + srow * 1024;
  char* sdst1 = (char*)&Bs[1][0] + srow * 1024;

  const int brow = l & 15;
  const unsigned lanep = (unsigned)((l >> 4) << 4);
  const unsigned xorv = (unsigned)((brow & 7) << 4);
  const char* bbase0 = (const char*)&Bs[0][0] + brow * 1024;
  const char* bbase1 = (const char*)&Bs[1][0] + brow * 1024;

  f4v mr = {-1e30f, -1e30f, -1e30f, -1e30f};
  f4v sr = {0.f, 0.f, 0.f, 0.f};

  {
    const char* src = (const char*)(wopb + (size_t)(c0 + srow) * E_) + scb;
    s8v g0 = *reinterpret_cast<const s8v*>(src);
    s8v g1 = *reinterpret_cast<const s8v*>(src + 16);
    *reinterpret_cast<s8v*>(sdst0 + ((unsigned)scb ^ sxr)) = g0;
    *reinterpret_cast<s8v*>(sdst0 + (((unsigned)scb + 16u) ^ sxr)) = g1;
  }
  __syncthreads();

  for (int tt = 0; tt < LSE_TILES; tt++) {
    int cur = tt & 1;
    bool more = (tt + 1) < LSE_TILES;
    s8v g0, g1;
    if (more) {
      const char* src = (const char*)(wopb + (size_t)(c0 + (tt + 1) * 16 + srow) * E_) + scb;
      g0 = *reinterpret_cast<const s8v*>(src);
      g1 = *reinterpret_cast<const s8v*>(src + 16);
    }
    const char* bbase = cur ? bbase1 : bbase0;
    f4v acc = {0.f, 0.f, 0.f, 0.f};
#pragma unroll
    for (int kk = 0; kk < 16; kk++) {
      unsigned off = ((unsigned)(kk * 64) + lanep) ^ xorv;
      s8v b = *reinterpret_cast<const s8v*>(bbase + off);
      acc = __builtin_amdgcn_mfma_f32_16x16x32_bf16(afr[kk], b, acc, 0, 0, 0);
    }
    float bv = bop[c0 + tt * 16 + (l & 15)];
#pragma unroll
    for (int i = 0; i < 4; i++) {
      float v = acc[i] + bv;
      if (v <= mr[i]) {
        sr[i] += __expf(v - mr[i]);
      } else {
        sr[i] = sr[i] * __expf(mr[i] - v) + 1.f;
        mr[i] = v;
      }
    }
    if (more) {
      char* sdst = cur ? sdst0 : sdst1;
      *reinterpret_cast<s8v*>(sdst + ((unsigned)scb ^ sxr)) = g0;
      *reinterpret_cast<s8v*>(sdst + (((unsigned)scb + 16u) ^ sxr)) = g1;
      __syncthreads();
    }
  }

  for (int sh = 1; sh < 16; sh <<= 1) {
#pragma unroll
    for (int i = 0; i < 4; i++) {
      float om = __shfl_xor(mr[i], sh, 64);
      float os = __shfl_xor(sr[i], sh, 64);
      float mn = fmaxf(mr[i], om);
      sr[i] = sr[i] * __expf(mr[i] - mn) + os * __expf(om - mn);
      mr[i] = mn;
    }
  }
  if ((l & 15) == 0) {
#pragma unroll
    for (int i = 0; i < 4; i++) {
      int row = r0 + (l >> 4) * 4 + i;
      if (row < NR_) {
        size_t o = ((size_t)row * LSE_NCH + blockIdx.x) * 2;
        part[o] = mr[i];
        part[o + 1] = sr[i];
      }
    }
  }
}

__global__ void k_final(const float* __restrict__ part, const ushort* __restrict__ logitb,
                        const float* __restrict__ Wop, const float* __restrict__ bop,
                        const int* __restrict__ y, float* __restrict__ nll) {
  int i = blockIdx.x * 256 + threadIdx.x;
  if (i >= NR_) return;
  float m = -1e30f;
  for (int c = 0; c < LSE_NCH; c++) m = fmaxf(m, part[((size_t)i * LSE_NCH + c) * 2]);
  float s = 0.f;
  for (int c = 0; c < LSE_NCH; c++) {
    size_t o = ((size_t)i * LSE_NCH + c) * 2;
    s += part[o + 1] * __expf(part[o] - m);
  }
  float lse = m + logf(s);
  int tgt = y[i + B_];
  float v = 0.f;
  if (tgt != 0) {
    const ushort* lr = logitb + (size_t)i * E_;
    const float* wr = Wop + (size_t)tgt * E_;
    float dot = 0.f;
    for (int k = 0; k < E_; k++) dot += b2f(lr[k]) * wr[k];
    dot += bop[tgt];
    v = lse - dot;
  }
  nll[i] = v;
}

__global__ void k_reduce(const float* __restrict__ nll, float* __restrict__ out) {
  __shared__ float sh[256];
  float a = 0.f;
  for (int i = threadIdx.x; i < NR_; i += 256) a += nll[i];
  sh[threadIdx.x] = a;
  __syncthreads();
  for (int s = 128; s; s >>= 1) {
    if (threadIdx.x < s) sh[threadIdx.x] += sh[threadIdx.x + s];
    __syncthreads();
  }
  if (threadIdx.x == 0) out[0] = sh[0];
}

// ---------------- host ----------------

extern "C" void kernel_launch(void* const* d_in, const int* in_sizes, int n_in,
                              void* d_out, int out_size, void* d_ws, size_t ws_size,
                              hipStream_t stream) {
  const float* ctx  = (const float*)d_in[0];
  const int*   y    = (const int*)d_in[1];
  const float* emb  = (const float*)d_in[2];
  const float* Wih0 = (const float*)d_in[3];
  const float* Whh0 = (const float*)d_in[4];
  const float* bih0 = (const float*)d_in[5];
  const float* bhh0 = (const float*)d_in[6];
  const float* Wih1 = (const float*)d_in[7];
  const float* Whh1 = (const float*)d_in[8];
  const float* bih1 = (const float*)d_in[9];
  const float* bhh1 = (const float*)d_in[10];
  const float* Wc2c = (const float*)d_in[11];
  const float* Wh2c = (const float*)d_in[12];
  const float* wmlp = (const float*)d_in[13];
  const float* Wc2h = (const float*)d_in[14];
  const float* Who  = (const float*)d_in[15];
  const float* bho  = (const float*)d_in[16];
  const float* Wop  = (const float*)d_in[17];
  const float* bop  = (const float*)d_in[18];

  char* ws = (char*)d_ws;
  size_t off = 0;
  auto alloc = [&](size_t bytes) { void* p = ws + off; off += (bytes + 255) & ~size_t(255); return p; };

  ushort* ctxb   = (ushort*)alloc((size_t)S_ * B_ * C_ * 2);
  ushort* wih0b  = (ushort*)alloc((size_t)3 * H_ * E_ * 2);
  ushort* whh0b  = (ushort*)alloc((size_t)3 * H_ * H_ * 2);
  ushort* wh2cb  = (ushort*)alloc((size_t)C_ * H_ * 2);
  ushort* wc2hT  = (ushort*)alloc((size_t)C_ * H_ * 2);
  ushort* wih1b  = (ushort*)alloc((size_t)3 * H_ * H_ * 2);
  ushort* whh1b  = (ushort*)alloc((size_t)3 * H_ * H_ * 2);
  ushort* whob   = (ushort*)alloc((size_t)E_ * H_ * 2);
  ushort* wopb   = (ushort*)alloc((size_t)V_ * E_ * 2);
  ushort* wc2cb  = (ushort*)alloc((size_t)C_ * C_ * 2);
  ushort* wcombb = (ushort*)alloc((size_t)3 * H_ * C_ * 2);
  ushort* xb     = (ushort*)alloc((size_t)NR_ * E_ * 2);
  ushort* gi0b   = (ushort*)alloc((size_t)NR_ * 3 * H_ * 2);
  ushort* ctxpb  = (ushort*)alloc((size_t)S_ * B_ * C_ * 2);
  float*  H2f    = (float*)alloc((size_t)TS_ * B_ * H_ * 4);
  ushort* H2b    = (ushort*)alloc((size_t)TS_ * B_ * H_ * 2);
  float*  h0f    = (float*)alloc((size_t)B_ * H_ * 4);
  ushort* h0b    = (ushort*)alloc((size_t)B_ * H_ * 2);
  float*  h1f    = (float*)alloc((size_t)B_ * H_ * 4);
  ushort* h1b    = (ushort*)alloc((size_t)B_ * H_ * 2);
  float*  hidf   = (float*)alloc((size_t)B_ * C_ * 4);
  float*  gh1f   = (float*)alloc((size_t)B_ * 3 * H_ * 4);
  ushort* zrawb  = (ushort*)alloc((size_t)B_ * C_ * 2);
  ushort* logitb = (ushort*)alloc((size_t)NR_ * E_ * 2);
  float*  part   = (float*)alloc((size_t)2048 * LSE_NCH * 2 * 4);
  float*  nllb   = (float*)alloc((size_t)2048 * 4);
  unsigned* bar  = (unsigned*)alloc(256);
  (void)ws_size; (void)in_sizes; (void)n_in; (void)out_size;

  (void)hipMemsetAsync(h0f, 0, (size_t)B_ * H_ * 4, stream);
  (void)hipMemsetAsync(h0b, 0, (size_t)B_ * H_ * 2, stream);
  (void)hipMemsetAsync(bar, 0, 256, stream);

  auto cgrid = [](int n) { return dim3((unsigned)((n / 4 + 255) / 256)); };
  k_convert<<<cgrid(S_ * B_ * C_), 256, 0, stream>>>(ctx, ctxb, S_ * B_ * C_);
  k_convert<<<cgrid(3 * H_ * E_), 256, 0, stream>>>(Wih0, wih0b, 3 * H_ * E_);
  k_convert<<<cgrid(3 * H_ * H_), 256, 0, stream>>>(Whh0, whh0b, 3 * H_ * H_);
  k_convert<<<cgrid(C_ * H_), 256, 0, stream>>>(Wh2c, wh2cb, C_ * H_);
  k_convert<<<cgrid(3 * H_ * H_), 256, 0, stream>>>(Wih1, wih1b, 3 * H_ * H_);
  k_convert<<<cgrid(3 * H_ * H_), 256, 0, stream>>>(Whh1, whh1b, 3 * H_ * H_);
  k_convert<<<cgrid(E_ * H_), 256, 0, stream>>>(Who, whob, E_ * H_);
  k_convert<<<cgrid(V_ * E_), 256, 0, stream>>>(Wop, wopb, V_ * E_);
  k_convert<<<cgrid(C_ * C_), 256, 0, stream>>>(Wc2c, wc2cb, C_ * C_);
  k_convert_T<<<dim3(4096), 256, 0, stream>>>(Wc2h, wc2hT);

  k_gather<<<dim3((NR_ * (E_ / 4) + 255) / 256), 256, 0, stream>>>(y, emb, xb);

  gemm_bt<<<dim3(3 * H_ / 64, NR_ / 64), 256, 0, stream>>>(xb, wih0b, bih0, nullptr, gi0b,
                                                           NR_, 3 * H_, E_, 0);
  gemm_bt<<<dim3(C_ / 64, S_ * B_ / 64), 256, 0, stream>>>(ctxb, wc2cb, nullptr, nullptr, ctxpb,
                                                           S_ * B_, C_, C_, 0);
  gemm_bt<<<dim3(C_ / 64, 3 * H_ / 64), 256, 0, stream>>>(wih1b, wc2hT, nullptr, nullptr, wcombb,
                                                          3 * H_, C_, H_, 0);

  LoopP p;
  p.whh0b = whh0b; p.gi0b = gi0b; p.wh2cb = wh2cb; p.whh1b = whh1b;
  p.wcombb = wcombb; p.ctxpb = ctxpb; p.ctxb = ctxb;
  p.bhh0 = bhh0; p.bih1 = bih1; p.bhh1 = bhh1; p.wmlp = wmlp;
  p.h0f = h0f; p.h0b = h0b;
  p.h1f = h1f; p.h1b = h1b; p.hidf = hidf; p.gh1f = gh1f; p.zrawb = zrawb;
  p.H2f = H2f; p.H2b = H2b; p.bar = bar;
  void* args[] = { (void*)&p };
  (void)hipLaunchCooperativeKernel(k_loop, dim3(NBLK_), dim3(256), args, 0, stream);

  gemm_bt<<<dim3(E_ / 64, NR_ / 64), 256, 0, stream>>>(H2b, whob, bho, nullptr, logitb,
                                                       NR_, E_, H_, 1);
  k_lse2<<<dim3(LSE_NCH, 16), 512, 0, stream>>>(logitb, wopb, bop, part);
  k_final<<<dim3(8), 256, 0, stream>>>(part, logitb, Wop, bop, y, nllb);
  k_reduce<<<dim3(1), 256, 0, stream>>>(nllb, (float*)d_out);
}

// Round 6
// 3478.602 us; speedup vs baseline: 2.2063x; 1.1918x over previous
//
#include <hip/hip_runtime.h>

#define S_ 50
#define B_ 64
#define T_ 32
#define E_ 512
#define H_ 1024
#define C_ 1024
#define V_ 32000
#define TS_ 31            // T-1 steps
#define NR_ 1984          // TS_*B_ rows
#define NBLK_ 256         // persistent-loop grid size

typedef __attribute__((ext_vector_type(8))) short s8v;   // 8 x bf16 bits
typedef __attribute__((ext_vector_type(4))) float f4v;   // MFMA acc / float4

static __device__ __forceinline__ float b2f(ushort u) {
  unsigned x = ((unsigned)u) << 16; float f; __builtin_memcpy(&f, &x, 4); return f;
}
static __device__ __forceinline__ ushort f2b(float f) {
  unsigned x; __builtin_memcpy(&x, &f, 4);
  x = x + 0x7FFFu + ((x >> 16) & 1u);
  return (ushort)(x >> 16);
}
static __device__ __forceinline__ float sigm(float x) { return 1.f / (1.f + __expf(-x)); }

// ---- coherence-point I/O: plain wide loads/stores with sc0 sc1 (bypass L1/L2) ----
static __device__ __forceinline__ s8v ld_sc16(const void* p) {
  s8v v;
  asm volatile("global_load_dwordx4 %0, %1, off sc0 sc1" : "=v"(v) : "v"(p) : "memory");
  return v;
}
static __device__ __forceinline__ f4v ld_scf4(const float* p) {
  f4v v;
  asm volatile("global_load_dwordx4 %0, %1, off sc0 sc1" : "=v"(v) : "v"(p) : "memory");
  return v;
}
static __device__ __forceinline__ float ld_scf(const float* p) {
  float v;
  asm volatile("global_load_dword %0, %1, off sc0 sc1" : "=v"(v) : "v"(p) : "memory");
  return v;
}
static __device__ __forceinline__ void st_scf(float* p, float v) {
  asm volatile("global_store_dword %0, %1, off sc0 sc1" :: "v"(p), "v"(v) : "memory");
}
static __device__ __forceinline__ void st_sc8(void* p, unsigned long long v) {
  asm volatile("global_store_dwordx2 %0, %1, off sc0 sc1" :: "v"(p), "v"(v) : "memory");
}
#define SCW0 do { asm volatile("s_waitcnt vmcnt(0)" ::: "memory"); __builtin_amdgcn_sched_barrier(0); } while (0)
#define SCW4 do { asm volatile("s_waitcnt vmcnt(4)" ::: "memory"); __builtin_amdgcn_sched_barrier(0); } while (0)

// A-frag: lane holds row (l&15), k = kb + 8*(l>>4) + j   (16B contiguous load)
static __device__ __forceinline__ s8v ldfrag(const ushort* base, int ld, int row0, int kb, int lane) {
  const ushort* p = base + (size_t)(row0 + (lane & 15)) * ld + (kb + ((lane >> 4) << 3));
  return *reinterpret_cast<const s8v*>(p);
}

// B-frag from swizzled LDS: row r (2KB rows), byte col = kb*2 + (l>>4)*16, XOR (r&7)<<4
static __device__ __forceinline__ s8v ldsfrag(const ushort* base, int r, int kb, int lane) {
  unsigned o = (unsigned)r * 2048u +
               (((unsigned)(kb * 2 + ((lane >> 4) << 4))) ^ ((unsigned)((r & 7) << 4)));
  return *reinterpret_cast<const s8v*>((const char*)base + o);
}

// ---------------- conversions / gathers ----------------

__global__ void k_convert(const float* __restrict__ s, ushort* __restrict__ d, int n) {
  int i = (blockIdx.x * 256 + threadIdx.x) * 4;
  if (i >= n) return;
  float4 v = *reinterpret_cast<const float4*>(s + i);
  ushort4 o; o.x = f2b(v.x); o.y = f2b(v.y); o.z = f2b(v.z); o.w = f2b(v.w);
  *reinterpret_cast<ushort4*>(d + i) = o;
}

// W_c2h (H x C) -> bf16 transposed (C x H)
__global__ void k_convert_T(const float* __restrict__ s, ushort* __restrict__ d) {
  int gid = blockIdx.x * 256 + threadIdx.x;
  int h = gid & 1023, c = gid >> 10;
  d[(size_t)c * 1024 + h] = f2b(s[(size_t)h * 1024 + c]);
}

__global__ void k_gather(const int* __restrict__ y, const float* __restrict__ emb,
                         ushort* __restrict__ xb) {
  int gid = blockIdx.x * 256 + threadIdx.x;
  if (gid >= NR_ * (E_ / 4)) return;
  int i = gid >> 7;
  int c = (gid & 127) << 2;
  int idx = y[i];
  float4 v = make_float4(0.f, 0.f, 0.f, 0.f);
  if (idx != 0) v = *reinterpret_cast<const float4*>(emb + (size_t)idx * E_ + c);
  ushort4 o; o.x = f2b(v.x); o.y = f2b(v.y); o.z = f2b(v.z); o.w = f2b(v.w);
  *reinterpret_cast<ushort4*>(xb + (size_t)i * E_ + c) = o;
}

// ---------------- generic GEMM: out[m,n] = sum_k A[m,k]*B[n,k] (+bias) (opt tanh) ----------------
__global__ void gemm_bt(const ushort* __restrict__ A, const ushort* __restrict__ Bm,
                        const float* __restrict__ bias, float* __restrict__ outF,
                        ushort* __restrict__ outB, int M, int N, int K, int act) {
  int l = threadIdx.x & 63, w = threadIdx.x >> 6;
  int m0 = blockIdx.y * 64 + w * 16;
  int n0 = blockIdx.x * 64;
  f4v acc[4] = {{0.f,0.f,0.f,0.f},{0.f,0.f,0.f,0.f},{0.f,0.f,0.f,0.f},{0.f,0.f,0.f,0.f}};
  for (int kb = 0; kb < K; kb += 32) {
    s8v a = ldfrag(A, K, m0, kb, l);
#pragma unroll
    for (int nt = 0; nt < 4; nt++) {
      s8v b = ldfrag(Bm, K, n0 + nt * 16, kb, l);
      acc[nt] = __builtin_amdgcn_mfma_f32_16x16x32_bf16(a, b, acc[nt], 0, 0, 0);
    }
  }
  int rb = (l >> 4) * 4;
  int col = l & 15;
#pragma unroll
  for (int nt = 0; nt < 4; nt++) {
    int n = n0 + nt * 16 + col;
    float bv = bias ? bias[n] : 0.f;
#pragma unroll
    for (int i = 0; i < 4; i++) {
      int m = m0 + rb + i;
      float v = acc[nt][i] + bv;
      if (act) v = tanhf(v);
      size_t o = (size_t)m * N + n;
      if (outF) outF[o] = v;
      if (outB) outB[o] = f2b(v);
    }
  }
}

// ---------------- persistent sequential loop (cooperative, flag-synced) ----------------

struct LoopP {
  const ushort* whh0b; const ushort* gi0b; const ushort* wh2cb; const ushort* whh1b;
  const ushort* wcombb; const ushort* ctxpb; const ushort* ctxb;
  const float* bhh0; const float* bih1; const float* bhh1; const float* wmlp;
  const float* h0f; const ushort* h0b;
  float* h1f; ushort* h1b; float* hidf; float* gh1f; ushort* zrawb;
  float* H2f; ushort* H2b;
  unsigned* flags;   // (t*5+k) cache lines; 0=fA 1=fH 2=fG 3=fZ 4=fD; memset 0 per launch
};

static __device__ __forceinline__ unsigned* flg(unsigned* base, int t, int k) {
  return (unsigned*)((char*)base + (((size_t)t * 5 + k) << 6));
}
// arrive: drain stores to coherence point, then +1 (relaxed agent RMW at MALL)
static __device__ __forceinline__ void arrive(unsigned* f) {
  asm volatile("s_waitcnt vmcnt(0)" ::: "memory");
  __syncthreads();
  if (threadIdx.x == 0)
    __hip_atomic_fetch_add(f, 1u, __ATOMIC_RELAXED, __HIP_MEMORY_SCOPE_AGENT);
}
static __device__ __forceinline__ void waitflag(unsigned* f, unsigned tgt) {
  __syncthreads();
  if (threadIdx.x == 0) {
    while (__hip_atomic_load(f, __ATOMIC_RELAXED, __HIP_MEMORY_SCOPE_AGENT) < tgt)
      __builtin_amdgcn_s_sleep(1);
  }
  __syncthreads();
}

// roles: 0 (blk 0-63)=GRU0/Whh0 ; 1 (64-127)=GRU1/Wcomb ; 2 (128-191)=hid/Wh2c + attn ; 3 (192-255)=gh1/Whh1
__global__ __launch_bounds__(256) void k_loop(LoopP p) {
  __shared__ __align__(16) ushort ldsW[48 * 1024];   // 96KB, 48 rows x 2KB, XOR-swizzled
  __shared__ __align__(16) float hs[C_];
  __shared__ float sc[S_];
  __shared__ float al[S_];
  __shared__ __align__(8) ushort stile[64 * 16];     // bf16 epilogue re-layout tile

  const int tid = threadIdx.x;
  const int blk = blockIdx.x;
  const int l = tid & 63, w = tid >> 6;
  const int role = blk >> 6;
  const int sub = blk & 63;

  // ---- stage this block's weight slice into swizzled LDS (once) ----
  {
    const ushort* src;
    int nrows;
    if (role == 0)      { src = p.whh0b; nrows = 48; }
    else if (role == 1) { src = p.wcombb; nrows = 48; }
    else if (role == 2) { src = p.wh2cb; nrows = 16; }
    else                { src = p.whh1b; nrows = 48; }
    for (int idx = tid; idx < nrows * 128; idx += 256) {
      int r = idx >> 7, c = idx & 127;
      int grow;
      if (role == 0 || role == 1) grow = (r >> 4) * H_ + sub * 16 + (r & 15);
      else if (role == 2)         grow = sub * 16 + r;
      else                        grow = sub * 48 + r;
      s8v v = *reinterpret_cast<const s8v*>(src + (size_t)grow * 1024 + c * 8);
      unsigned o = (unsigned)r * 2048u + (((unsigned)(c * 16)) ^ ((unsigned)((r & 7) << 4)));
      *reinterpret_cast<s8v*>((char*)ldsW + o) = v;
    }
    __syncthreads();
  }

  const int rr = l & 15;

  for (int t = 0; t < TS_; t++) {
    if (role == 0) {
      // ---- phase A: h1 = GRU0(h_prev) ----
      if (t) waitflag(flg(p.flags, t - 1, 4), 64);
      const float*  hpf = t ? (p.H2f + (size_t)(t - 1) * B_ * H_) : p.h0f;
      const ushort* hpb = t ? (p.H2b + (size_t)(t - 1) * B_ * H_) : p.h0b;
      const ushort* gi0t = p.gi0b + (size_t)t * B_ * 3 * H_;
      int m0 = w * 16;
      const ushort* abase = hpb + (size_t)(m0 + (l & 15)) * H_ + ((l >> 4) << 3);
      s8v stg[2][4];
#pragma unroll
      for (int i = 0; i < 4; i++) stg[0][i] = ld_sc16(abase + i * 32);
      f4v aR = {0.f,0.f,0.f,0.f}, aZ = {0.f,0.f,0.f,0.f}, aN = {0.f,0.f,0.f,0.f};
#pragma unroll
      for (int bb = 0; bb < 8; bb++) {
        if (bb < 7) {
#pragma unroll
          for (int i = 0; i < 4; i++) stg[(bb + 1) & 1][i] = ld_sc16(abase + (bb + 1) * 128 + i * 32);
          SCW4;
        } else {
          SCW0;
        }
#pragma unroll
        for (int i = 0; i < 4; i++) {
          int kb = bb * 128 + i * 32;
          s8v av = stg[bb & 1][i];
          aR = __builtin_amdgcn_mfma_f32_16x16x32_bf16(av, ldsfrag(ldsW, rr, kb, l), aR, 0, 0, 0);
          aZ = __builtin_amdgcn_mfma_f32_16x16x32_bf16(av, ldsfrag(ldsW, 16 + rr, kb, l), aZ, 0, 0, 0);
          aN = __builtin_amdgcn_mfma_f32_16x16x32_bf16(av, ldsfrag(ldsW, 32 + rr, kb, l), aN, 0, 0, 0);
        }
      }
      int rb = (l >> 4) * 4, c15 = l & 15, c = sub * 16 + c15;
      float hp[4];
#pragma unroll
      for (int i = 0; i < 4; i++) hp[i] = ld_scf(&hpf[(size_t)(m0 + rb + i) * H_ + c]);
      SCW0;
#pragma unroll
      for (int i = 0; i < 4; i++) {
        int m = m0 + rb + i;
        const ushort* gi = gi0t + (size_t)m * (3 * H_);
        float gir = b2f(gi[c]), giz = b2f(gi[H_ + c]), gin = b2f(gi[2 * H_ + c]);
        float ghr = aR[i] + p.bhh0[c], ghz = aZ[i] + p.bhh0[H_ + c], ghn = aN[i] + p.bhh0[2 * H_ + c];
        float r = sigm(gir + ghr);
        float zg = sigm(giz + ghz);
        float nn = tanhf(gin + r * ghn);
        float h1 = (1.f - zg) * nn + zg * hp[i];
        st_scf(&p.h1f[(size_t)m * H_ + c], h1);
        stile[m * 16 + c15] = f2b(h1);
      }
      __syncthreads();
      {
        int row = tid >> 2, ch = tid & 3;
        unsigned long long v = *reinterpret_cast<unsigned long long*>(&stile[row * 16 + ch * 4]);
        st_sc8(&p.h1b[(size_t)row * H_ + sub * 16 + ch * 4], v);
      }
      arrive(flg(p.flags, t, 0));

    } else if (role == 2) {
      // ---- hid = h1 @ Wh2c.T (col slice) ----
      waitflag(flg(p.flags, t, 0), 64);
      int m0 = w * 16;
      const ushort* abase = p.h1b + (size_t)(m0 + (l & 15)) * H_ + ((l >> 4) << 3);
      s8v stg[2][4];
#pragma unroll
      for (int i = 0; i < 4; i++) stg[0][i] = ld_sc16(abase + i * 32);
      f4v acc = {0.f,0.f,0.f,0.f};
#pragma unroll
      for (int bb = 0; bb < 8; bb++) {
        if (bb < 7) {
#pragma unroll
          for (int i = 0; i < 4; i++) stg[(bb + 1) & 1][i] = ld_sc16(abase + (bb + 1) * 128 + i * 32);
          SCW4;
        } else {
          SCW0;
        }
#pragma unroll
        for (int i = 0; i < 4; i++) {
          int kb = bb * 128 + i * 32;
          acc = __builtin_amdgcn_mfma_f32_16x16x32_bf16(stg[bb & 1][i], ldsfrag(ldsW, rr, kb, l), acc, 0, 0, 0);
        }
      }
      int rb = (l >> 4) * 4, c = sub * 16 + (l & 15);
#pragma unroll
      for (int i = 0; i < 4; i++) st_scf(&p.hidf[(size_t)(m0 + rb + i) * C_ + c], acc[i]);
      arrive(flg(p.flags, t, 1));

      // ---- attention -> z_raw (b = sub) ----
      waitflag(flg(p.flags, t, 1), 64);
      int b = sub;
      f4v hv = ld_scf4(&p.hidf[(size_t)b * C_ + tid * 4]);
      SCW0;
      *reinterpret_cast<f4v*>(&hs[tid * 4]) = hv;
      __syncthreads();
      for (int s = w; s < S_; s += 4) {
        const ushort* row = p.ctxpb + ((size_t)s * B_ + b) * C_;
        float a = 0.f;
        for (int c = l; c < C_; c += 64) a += tanhf(b2f(row[c]) + hs[c]) * p.wmlp[c];
        for (int m = 32; m; m >>= 1) a += __shfl_xor(a, m, 64);
        if (l == 0) sc[s] = a;
      }
      __syncthreads();
      float mx = -1e30f;
      for (int s = 0; s < S_; s++) mx = fmaxf(mx, sc[s]);
      float sm = 0.f;
      for (int s = 0; s < S_; s++) sm += __expf(sc[s] - mx);
      if (tid < S_) al[tid] = __expf(sc[tid] - mx) / sm;
      __syncthreads();
      int c0 = tid * 4;
      float a0 = 0.f, a1 = 0.f, a2 = 0.f, a3 = 0.f;
      for (int s = 0; s < S_; s++) {
        float a = al[s];
        ushort4 cv = *reinterpret_cast<const ushort4*>(p.ctxb + ((size_t)s * B_ + b) * C_ + c0);
        a0 += a * b2f(cv.x); a1 += a * b2f(cv.y); a2 += a * b2f(cv.z); a3 += a * b2f(cv.w);
      }
      ushort4 o; o.x = f2b(a0); o.y = f2b(a1); o.z = f2b(a2); o.w = f2b(a3);
      unsigned long long pk; __builtin_memcpy(&pk, &o, 8);
      st_sc8(p.zrawb + (size_t)b * C_ + c0, pk);
      arrive(flg(p.flags, t, 3));

    } else if (role == 3) {
      // ---- gh1 = h1 @ Whh1.T (48-col slice) ----
      waitflag(flg(p.flags, t, 0), 64);
      int m0 = w * 16;
      const ushort* abase = p.h1b + (size_t)(m0 + (l & 15)) * H_ + ((l >> 4) << 3);
      s8v stg[2][4];
#pragma unroll
      for (int i = 0; i < 4; i++) stg[0][i] = ld_sc16(abase + i * 32);
      f4v a0 = {0.f,0.f,0.f,0.f}, a1 = {0.f,0.f,0.f,0.f}, a2 = {0.f,0.f,0.f,0.f};
#pragma unroll
      for (int bb = 0; bb < 8; bb++) {
        if (bb < 7) {
#pragma unroll
          for (int i = 0; i < 4; i++) stg[(bb + 1) & 1][i] = ld_sc16(abase + (bb + 1) * 128 + i * 32);
          SCW4;
        } else {
          SCW0;
        }
#pragma unroll
        for (int i = 0; i < 4; i++) {
          int kb = bb * 128 + i * 32;
          s8v av = stg[bb & 1][i];
          a0 = __builtin_amdgcn_mfma_f32_16x16x32_bf16(av, ldsfrag(ldsW, rr, kb, l), a0, 0, 0, 0);
          a1 = __builtin_amdgcn_mfma_f32_16x16x32_bf16(av, ldsfrag(ldsW, 16 + rr, kb, l), a1, 0, 0, 0);
          a2 = __builtin_amdgcn_mfma_f32_16x16x32_bf16(av, ldsfrag(ldsW, 32 + rr, kb, l), a2, 0, 0, 0);
        }
      }
      int rb = (l >> 4) * 4, cb = sub * 48 + (l & 15);
#pragma unroll
      for (int i = 0; i < 4; i++) {
        int m = m0 + rb + i;
        st_scf(&p.gh1f[(size_t)m * (3 * H_) + cb],      a0[i]);
        st_scf(&p.gh1f[(size_t)m * (3 * H_) + cb + 16], a1[i]);
        st_scf(&p.gh1f[(size_t)m * (3 * H_) + cb + 32], a2[i]);
      }
      arrive(flg(p.flags, t, 2));

    } else {
      // ---- role 1: h2 = GRU1(z_raw, h1) ----
      waitflag(flg(p.flags, t, 3), 64);
      waitflag(flg(p.flags, t, 2), 64);
      int m0 = w * 16;
      float* h2f = p.H2f + (size_t)t * B_ * H_;
      ushort* h2b = p.H2b + (size_t)t * B_ * H_;
      const ushort* abase = p.zrawb + (size_t)(m0 + (l & 15)) * C_ + ((l >> 4) << 3);
      s8v stg[2][4];
#pragma unroll
      for (int i = 0; i < 4; i++) stg[0][i] = ld_sc16(abase + i * 32);
      f4v aR = {0.f,0.f,0.f,0.f}, aZ = {0.f,0.f,0.f,0.f}, aN = {0.f,0.f,0.f,0.f};
#pragma unroll
      for (int bb = 0; bb < 8; bb++) {
        if (bb < 7) {
#pragma unroll
          for (int i = 0; i < 4; i++) stg[(bb + 1) & 1][i] = ld_sc16(abase + (bb + 1) * 128 + i * 32);
          SCW4;
        } else {
          SCW0;
        }
#pragma unroll
        for (int i = 0; i < 4; i++) {
          int kb = bb * 128 + i * 32;
          s8v av = stg[bb & 1][i];
          aR = __builtin_amdgcn_mfma_f32_16x16x32_bf16(av, ldsfrag(ldsW, rr, kb, l), aR, 0, 0, 0);
          aZ = __builtin_amdgcn_mfma_f32_16x16x32_bf16(av, ldsfrag(ldsW, 16 + rr, kb, l), aZ, 0, 0, 0);
          aN = __builtin_amdgcn_mfma_f32_16x16x32_bf16(av, ldsfrag(ldsW, 32 + rr, kb, l), aN, 0, 0, 0);
        }
      }
      int rb = (l >> 4) * 4, c15 = l & 15, c = sub * 16 + c15;
      float gr[4], gz[4], gn[4], h1v[4];
#pragma unroll
      for (int i = 0; i < 4; i++) {
        int m = m0 + rb + i;
        gr[i]  = ld_scf(&p.gh1f[(size_t)m * (3 * H_) + c]);
        gz[i]  = ld_scf(&p.gh1f[(size_t)m * (3 * H_) + H_ + c]);
        gn[i]  = ld_scf(&p.gh1f[(size_t)m * (3 * H_) + 2 * H_ + c]);
        h1v[i] = ld_scf(&p.h1f[(size_t)m * H_ + c]);
      }
      SCW0;
#pragma unroll
      for (int i = 0; i < 4; i++) {
        int m = m0 + rb + i;
        float gir = aR[i] + p.bih1[c], giz = aZ[i] + p.bih1[H_ + c], gin = aN[i] + p.bih1[2 * H_ + c];
        float ghr = gr[i] + p.bhh1[c], ghz = gz[i] + p.bhh1[H_ + c], ghn = gn[i] + p.bhh1[2 * H_ + c];
        float r = sigm(gir + ghr);
        float zg = sigm(giz + ghz);
        float nn = tanhf(gin + r * ghn);
        float h2 = (1.f - zg) * nn + zg * h1v[i];
        st_scf(&h2f[(size_t)m * H_ + c], h2);
        stile[m * 16 + c15] = f2b(h2);
      }
      __syncthreads();
      {
        int row = tid >> 2, ch = tid & 3;
        unsigned long long v = *reinterpret_cast<unsigned long long*>(&stile[row * 16 + ch * 4]);
        st_sc8(&h2b[(size_t)row * H_ + sub * 16 + ch * 4], v);
      }
      arrive(flg(p.flags, t, 4));
    }
  }
}

// ---------------- epilogue: streaming LSE over vocab ----------------
#define LSE_NCH 40
#define LSE_TILES 50    // 16-col tiles per chunk (40*50*16 = 32000)

__global__ __launch_bounds__(512) void k_lse2(const ushort* __restrict__ logitb,
                                              const ushort* __restrict__ wopb,
                                              const float* __restrict__ bop,
                                              float* __restrict__ part) {
  __shared__ ushort Bs[2][16 * E_];   // 2 x 16KB (16 rows x 1024B)
  int tid = threadIdx.x, l = tid & 63, w = tid >> 6;
  int r0 = blockIdx.y * 128 + w * 16;
  int c0 = blockIdx.x * (LSE_TILES * 16);
  int arow = r0 + (l & 15);
  bool aok = arow < NR_;

  s8v afr[16];
#pragma unroll
  for (int kk = 0; kk < 16; kk++) {
    s8v z = {0,0,0,0,0,0,0,0};
    afr[kk] = aok ? *reinterpret_cast<const s8v*>(logitb + (size_t)arow * E_ + kk * 32 + ((l >> 4) << 3)) : z;
  }

  const int srow = tid >> 5;
  const int scb = (tid & 31) * 32;
  const unsigned sxr = (unsigned)((srow & 7) << 4);
  char* sdst0 = (char*)&Bs[0][0] + srow * 1024;
  char* sdst1 = (char*)&Bs[1][0] + srow * 1024;

  const int brow = l & 15;
  const unsigned lanep = (unsigned)((l >> 4) << 4);
  const unsigned xorv = (unsigned)((brow & 7) << 4);
  const char* bbase0 = (const char*)&Bs[0][0] + brow * 1024;
  const char* bbase1 = (const char*)&Bs[1][0] + brow * 1024;

  f4v mr = {-1e30f, -1e30f, -1e30f, -1e30f};
  f4v sr = {0.f, 0.f, 0.f, 0.f};

  {
    const char* src = (const char*)(wopb + (size_t)(c0 + srow) * E_) + scb;
    s8v g0 = *reinterpret_cast<const s8v*>(src);
    s8v g1 = *reinterpret_cast<const s8v*>(src + 16);
    *reinterpret_cast<s8v*>(sdst0 + ((unsigned)scb ^ sxr)) = g0;
    *reinterpret_cast<s8v*>(sdst0 + (((unsigned)scb + 16u) ^ sxr)) = g1;
  }
  __syncthreads();

  for (int tt = 0; tt < LSE_TILES; tt++) {
    int cur = tt & 1;
    bool more = (tt + 1) < LSE_TILES;
    s8v g0, g1;
    if (more) {
      const char* src = (const char*)(wopb + (size_t)(c0 + (tt + 1) * 16 + srow) * E_) + scb;
      g0 = *reinterpret_cast<const s8v*>(src);
      g1 = *reinterpret_cast<const s8v*>(src + 16);
    }
    const char* bbase = cur ? bbase1 : bbase0;
    f4v acc = {0.f, 0.f, 0.f, 0.f};
#pragma unroll
    for (int kk = 0; kk < 16; kk++) {
      unsigned off = ((unsigned)(kk * 64) + lanep) ^ xorv;
      s8v b = *reinterpret_cast<const s8v*>(bbase + off);
      acc = __builtin_amdgcn_mfma_f32_16x16x32_bf16(afr[kk], b, acc, 0, 0, 0);
    }
    float bv = bop[c0 + tt * 16 + (l & 15)];
#pragma unroll
    for (int i = 0; i < 4; i++) {
      float v = acc[i] + bv;
      if (v <= mr[i]) {
        sr[i] += __expf(v - mr[i]);
      } else {
        sr[i] = sr[i] * __expf(mr[i] - v) + 1.f;
        mr[i] = v;
      }
    }
    if (more) {
      char* sdst = cur ? sdst0 : sdst1;
      *reinterpret_cast<s8v*>(sdst + ((unsigned)scb ^ sxr)) = g0;
      *reinterpret_cast<s8v*>(sdst + (((unsigned)scb + 16u) ^ sxr)) = g1;
      __syncthreads();
    }
  }

  for (int sh = 1; sh < 16; sh <<= 1) {
#pragma unroll
    for (int i = 0; i < 4; i++) {
      float om = __shfl_xor(mr[i], sh, 64);
      float os = __shfl_xor(sr[i], sh, 64);
      float mn = fmaxf(mr[i], om);
      sr[i] = sr[i] * __expf(mr[i] - mn) + os * __expf(om - mn);
      mr[i] = mn;
    }
  }
  if ((l & 15) == 0) {
#pragma unroll
    for (int i = 0; i < 4; i++) {
      int row = r0 + (l >> 4) * 4 + i;
      if (row < NR_) {
        size_t o = ((size_t)row * LSE_NCH + blockIdx.x) * 2;
        part[o] = mr[i];
        part[o + 1] = sr[i];
      }
    }
  }
}

__global__ void k_final(const float* __restrict__ part, const ushort* __restrict__ logitb,
                        const float* __restrict__ Wop, const float* __restrict__ bop,
                        const int* __restrict__ y, float* __restrict__ nll) {
  int i = blockIdx.x * 256 + threadIdx.x;
  if (i >= NR_) return;
  float m = -1e30f;
  for (int c = 0; c < LSE_NCH; c++) m = fmaxf(m, part[((size_t)i * LSE_NCH + c) * 2]);
  float s = 0.f;
  for (int c = 0; c < LSE_NCH; c++) {
    size_t o = ((size_t)i * LSE_NCH + c) * 2;
    s += part[o + 1] * __expf(part[o] - m);
  }
  float lse = m + logf(s);
  int tgt = y[i + B_];
  float v = 0.f;
  if (tgt != 0) {
    const ushort* lr = logitb + (size_t)i * E_;
    const float* wr = Wop + (size_t)tgt * E_;
    float dot = 0.f;
    for (int k = 0; k < E_; k += 4) {
      ushort4 lv = *reinterpret_cast<const ushort4*>(lr + k);
      float4 wv = *reinterpret_cast<const float4*>(wr + k);
      dot += b2f(lv.x) * wv.x + b2f(lv.y) * wv.y + b2f(lv.z) * wv.z + b2f(lv.w) * wv.w;
    }
    dot += bop[tgt];
    v = lse - dot;
  }
  nll[i] = v;
}

__global__ void k_reduce(const float* __restrict__ nll, float* __restrict__ out) {
  __shared__ float sh[256];
  float a = 0.f;
  for (int i = threadIdx.x; i < NR_; i += 256) a += nll[i];
  sh[threadIdx.x] = a;
  __syncthreads();
  for (int s = 128; s; s >>= 1) {
    if (threadIdx.x < s) sh[threadIdx.x] += sh[threadIdx.x + s];
    __syncthreads();
  }
  if (threadIdx.x == 0) out[0] = sh[0];
}

// ---------------- host ----------------

extern "C" void kernel_launch(void* const* d_in, const int* in_sizes, int n_in,
                              void* d_out, int out_size, void* d_ws, size_t ws_size,
                              hipStream_t stream) {
  const float* ctx  = (const float*)d_in[0];
  const int*   y    = (const int*)d_in[1];
  const float* emb  = (const float*)d_in[2];
  const float* Wih0 = (const float*)d_in[3];
  const float* Whh0 = (const float*)d_in[4];
  const float* bih0 = (const float*)d_in[5];
  const float* bhh0 = (const float*)d_in[6];
  const float* Wih1 = (const float*)d_in[7];
  const float* Whh1 = (const float*)d_in[8];
  const float* bih1 = (const float*)d_in[9];
  const float* bhh1 = (const float*)d_in[10];
  const float* Wc2c = (const float*)d_in[11];
  const float* Wh2c = (const float*)d_in[12];
  const float* wmlp = (const float*)d_in[13];
  const float* Wc2h = (const float*)d_in[14];
  const float* Who  = (const float*)d_in[15];
  const float* bho  = (const float*)d_in[16];
  const float* Wop  = (const float*)d_in[17];
  const float* bop  = (const float*)d_in[18];

  char* ws = (char*)d_ws;
  size_t off = 0;
  auto alloc = [&](size_t bytes) { void* p = ws + off; off += (bytes + 255) & ~size_t(255); return p; };

  ushort* ctxb   = (ushort*)alloc((size_t)S_ * B_ * C_ * 2);
  ushort* wih0b  = (ushort*)alloc((size_t)3 * H_ * E_ * 2);
  ushort* whh0b  = (ushort*)alloc((size_t)3 * H_ * H_ * 2);
  ushort* wh2cb  = (ushort*)alloc((size_t)C_ * H_ * 2);
  ushort* wc2hT  = (ushort*)alloc((size_t)C_ * H_ * 2);
  ushort* wih1b  = (ushort*)alloc((size_t)3 * H_ * H_ * 2);
  ushort* whh1b  = (ushort*)alloc((size_t)3 * H_ * H_ * 2);
  ushort* whob   = (ushort*)alloc((size_t)E_ * H_ * 2);
  ushort* wopb   = (ushort*)alloc((size_t)V_ * E_ * 2);
  ushort* wc2cb  = (ushort*)alloc((size_t)C_ * C_ * 2);
  ushort* wcombb = (ushort*)alloc((size_t)3 * H_ * C_ * 2);
  ushort* xb     = (ushort*)alloc((size_t)NR_ * E_ * 2);
  ushort* gi0b   = (ushort*)alloc((size_t)NR_ * 3 * H_ * 2);
  ushort* ctxpb  = (ushort*)alloc((size_t)S_ * B_ * C_ * 2);
  float*  H2f    = (float*)alloc((size_t)TS_ * B_ * H_ * 4);
  ushort* H2b    = (ushort*)alloc((size_t)TS_ * B_ * H_ * 2);
  float*  h0f    = (float*)alloc((size_t)B_ * H_ * 4);
  ushort* h0b    = (ushort*)alloc((size_t)B_ * H_ * 2);
  float*  h1f    = (float*)alloc((size_t)B_ * H_ * 4);
  ushort* h1b    = (ushort*)alloc((size_t)B_ * H_ * 2);
  float*  hidf   = (float*)alloc((size_t)B_ * C_ * 4);
  float*  gh1f   = (float*)alloc((size_t)B_ * 3 * H_ * 4);
  ushort* zrawb  = (ushort*)alloc((size_t)B_ * C_ * 2);
  ushort* logitb = (ushort*)alloc((size_t)NR_ * E_ * 2);
  float*  part   = (float*)alloc((size_t)2048 * LSE_NCH * 2 * 4);
  float*  nllb   = (float*)alloc((size_t)2048 * 4);
  unsigned* flags = (unsigned*)alloc((size_t)TS_ * 5 * 64);
  (void)ws_size; (void)in_sizes; (void)n_in; (void)out_size;

  (void)hipMemsetAsync(h0f, 0, (size_t)B_ * H_ * 4, stream);
  (void)hipMemsetAsync(h0b, 0, (size_t)B_ * H_ * 2, stream);
  (void)hipMemsetAsync(flags, 0, (size_t)TS_ * 5 * 64, stream);

  auto cgrid = [](int n) { return dim3((unsigned)((n / 4 + 255) / 256)); };
  k_convert<<<cgrid(S_ * B_ * C_), 256, 0, stream>>>(ctx, ctxb, S_ * B_ * C_);
  k_convert<<<cgrid(3 * H_ * E_), 256, 0, stream>>>(Wih0, wih0b, 3 * H_ * E_);
  k_convert<<<cgrid(3 * H_ * H_), 256, 0, stream>>>(Whh0, whh0b, 3 * H_ * H_);
  k_convert<<<cgrid(C_ * H_), 256, 0, stream>>>(Wh2c, wh2cb, C_ * H_);
  k_convert<<<cgrid(3 * H_ * H_), 256, 0, stream>>>(Wih1, wih1b, 3 * H_ * H_);
  k_convert<<<cgrid(3 * H_ * H_), 256, 0, stream>>>(Whh1, whh1b, 3 * H_ * H_);
  k_convert<<<cgrid(E_ * H_), 256, 0, stream>>>(Who, whob, E_ * H_);
  k_convert<<<cgrid(V_ * E_), 256, 0, stream>>>(Wop, wopb, V_ * E_);
  k_convert<<<cgrid(C_ * C_), 256, 0, stream>>>(Wc2c, wc2cb, C_ * C_);
  k_convert_T<<<dim3(4096), 256, 0, stream>>>(Wc2h, wc2hT);

  k_gather<<<dim3((NR_ * (E_ / 4) + 255) / 256), 256, 0, stream>>>(y, emb, xb);

  gemm_bt<<<dim3(3 * H_ / 64, NR_ / 64), 256, 0, stream>>>(xb, wih0b, bih0, nullptr, gi0b,
                                                           NR_, 3 * H_, E_, 0);
  gemm_bt<<<dim3(C_ / 64, S_ * B_ / 64), 256, 0, stream>>>(ctxb, wc2cb, nullptr, nullptr, ctxpb,
                                                           S_ * B_, C_, C_, 0);
  gemm_bt<<<dim3(C_ / 64, 3 * H_ / 64), 256, 0, stream>>>(wih1b, wc2hT, nullptr, nullptr, wcombb,
                                                          3 * H_, C_, H_, 0);

  LoopP p;
  p.whh0b = whh0b; p.gi0b = gi0b; p.wh2cb = wh2cb; p.whh1b = whh1b;
  p.wcombb = wcombb; p.ctxpb = ctxpb; p.ctxb = ctxb;
  p.bhh0 = bhh0; p.bih1 = bih1; p.bhh1 = bhh1; p.wmlp = wmlp;
  p.h0f = h0f; p.h0b = h0b;
  p.h1f = h1f; p.h1b = h1b; p.hidf = hidf; p.gh1f = gh1f; p.zrawb = zrawb;
  p.H2f = H2f; p.H2b = H2b; p.flags = flags;
  void* args[] = { (void*)&p };
  (void)hipLaunchCooperativeKernel(k_loop, dim3(NBLK_), dim3(256), args, 0, stream);

  gemm_bt<<<dim3(E_ / 64, NR_ / 64), 256, 0, stream>>>(H2b, whob, bho, nullptr, logitb,
                                                       NR_, E_, H_, 1);
  k_lse2<<<dim3(LSE_NCH, 16), 512, 0, stream>>>(logitb, wopb, bop, part);
  k_final<<<dim3(8), 256, 0, stream>>>(part, logitb, Wop, bop, y, nllb);
  k_reduce<<<dim3(1), 256, 0, stream>>>(nllb, (float*)d_out);
}

// Round 7
// 2361.567 us; speedup vs baseline: 3.2498x; 1.4730x over previous
//
#include <hip/hip_runtime.h>

#define S_ 50
#define B_ 64
#define T_ 32
#define E_ 512
#define H_ 1024
#define C_ 1024
#define V_ 32000
#define TS_ 31            // T-1 steps
#define NR_ 1984          // TS_*B_ rows
#define NBLK_ 256         // persistent-loop grid size

typedef __attribute__((ext_vector_type(8))) short s8v;   // 8 x bf16 bits
typedef __attribute__((ext_vector_type(4))) float f4v;   // MFMA acc / float4

static __device__ __forceinline__ float b2f(ushort u) {
  unsigned x = ((unsigned)u) << 16; float f; __builtin_memcpy(&f, &x, 4); return f;
}
static __device__ __forceinline__ ushort f2b(float f) {
  unsigned x; __builtin_memcpy(&x, &f, 4);
  x = x + 0x7FFFu + ((x >> 16) & 1u);
  return (ushort)(x >> 16);
}
static __device__ __forceinline__ float sigm(float x) { return 1.f / (1.f + __expf(-x)); }
static __device__ __forceinline__ float tanh_fast(float x) {
  float e = __expf(2.f * x);
  return 1.f - 2.f / (e + 1.f);
}

// ---- coherence-point I/O (sc0 sc1: bypass L1/L2, straight to MALL) ----
static __device__ __forceinline__ void ld_b4(const ushort* a, s8v& v0, s8v& v1, s8v& v2, s8v& v3) {
  asm volatile(
    "global_load_dwordx4 %0, %4, off sc0 sc1\n\t"
    "global_load_dwordx4 %1, %4, off offset:64 sc0 sc1\n\t"
    "global_load_dwordx4 %2, %4, off offset:128 sc0 sc1\n\t"
    "global_load_dwordx4 %3, %4, off offset:192 sc0 sc1"
    : "=&v"(v0), "=&v"(v1), "=&v"(v2), "=&v"(v3)
    : "v"(a)
    : "memory");
}
static __device__ __forceinline__ f4v ld_scf4(const float* p) {
  f4v v;
  asm volatile("global_load_dwordx4 %0, %1, off sc0 sc1" : "=&v"(v) : "v"(p) : "memory");
  return v;
}
static __device__ __forceinline__ float ld_scf(const float* p) {
  float v;
  asm volatile("global_load_dword %0, %1, off sc0 sc1" : "=&v"(v) : "v"(p) : "memory");
  return v;
}
static __device__ __forceinline__ unsigned ld_scu(const unsigned* p) {
  unsigned v;
  asm volatile("global_load_dword %0, %1, off sc0 sc1\n\ts_waitcnt vmcnt(0)"
               : "=&v"(v) : "v"(p) : "memory");
  return v;
}
static __device__ __forceinline__ void st_scf(float* p, float v) {
  asm volatile("global_store_dword %0, %1, off sc0 sc1" :: "v"(p), "v"(v) : "memory");
}
static __device__ __forceinline__ void st_sc8(void* p, unsigned long long v) {
  asm volatile("global_store_dwordx2 %0, %1, off sc0 sc1" :: "v"(p), "v"(v) : "memory");
}
static __device__ __forceinline__ void st_scu(unsigned* p, unsigned v) {
  asm volatile("global_store_dword %0, %1, off sc0 sc1" :: "v"(p), "v"(v) : "memory");
}
#define STR_(x) #x
#define VMW(N) do { asm volatile("s_waitcnt vmcnt(" STR_(N) ")" ::: "memory"); __builtin_amdgcn_sched_barrier(0); } while (0)

// A-frag: lane holds row (l&15), k = kb + 8*(l>>4) + j   (16B contiguous load)
static __device__ __forceinline__ s8v ldfrag(const ushort* base, int ld, int row0, int kb, int lane) {
  const ushort* p = base + (size_t)(row0 + (lane & 15)) * ld + (kb + ((lane >> 4) << 3));
  return *reinterpret_cast<const s8v*>(p);
}

// B-frag from swizzled LDS: row r (2KB rows), byte col = kb*2 + (l>>4)*16, XOR (r&7)<<4
static __device__ __forceinline__ s8v ldsfrag(const ushort* base, int r, int kb, int lane) {
  unsigned o = (unsigned)r * 2048u +
               (((unsigned)(kb * 2 + ((lane >> 4) << 4))) ^ ((unsigned)((r & 7) << 4)));
  return *reinterpret_cast<const s8v*>((const char*)base + o);
}

// ---------------- conversions / gathers ----------------

__global__ void k_convert(const float* __restrict__ s, ushort* __restrict__ d, int n) {
  int i = (blockIdx.x * 256 + threadIdx.x) * 4;
  if (i >= n) return;
  float4 v = *reinterpret_cast<const float4*>(s + i);
  ushort4 o; o.x = f2b(v.x); o.y = f2b(v.y); o.z = f2b(v.z); o.w = f2b(v.w);
  *reinterpret_cast<ushort4*>(d + i) = o;
}

// W_c2h (H x C) -> bf16 transposed (C x H)
__global__ void k_convert_T(const float* __restrict__ s, ushort* __restrict__ d) {
  int gid = blockIdx.x * 256 + threadIdx.x;
  int h = gid & 1023, c = gid >> 10;
  d[(size_t)c * 1024 + h] = f2b(s[(size_t)h * 1024 + c]);
}

__global__ void k_gather(const int* __restrict__ y, const float* __restrict__ emb,
                         ushort* __restrict__ xb) {
  int gid = blockIdx.x * 256 + threadIdx.x;
  if (gid >= NR_ * (E_ / 4)) return;
  int i = gid >> 7;
  int c = (gid & 127) << 2;
  int idx = y[i];
  float4 v = make_float4(0.f, 0.f, 0.f, 0.f);
  if (idx != 0) v = *reinterpret_cast<const float4*>(emb + (size_t)idx * E_ + c);
  ushort4 o; o.x = f2b(v.x); o.y = f2b(v.y); o.z = f2b(v.z); o.w = f2b(v.w);
  *reinterpret_cast<ushort4*>(xb + (size_t)i * E_ + c) = o;
}

// ---------------- generic GEMM: out[m,n] = sum_k A[m,k]*B[n,k] (+bias) (opt tanh) ----------------
__global__ void gemm_bt(const ushort* __restrict__ A, const ushort* __restrict__ Bm,
                        const float* __restrict__ bias, float* __restrict__ outF,
                        ushort* __restrict__ outB, int M, int N, int K, int act) {
  int l = threadIdx.x & 63, w = threadIdx.x >> 6;
  int m0 = blockIdx.y * 64 + w * 16;
  int n0 = blockIdx.x * 64;
  f4v acc[4] = {{0.f,0.f,0.f,0.f},{0.f,0.f,0.f,0.f},{0.f,0.f,0.f,0.f},{0.f,0.f,0.f,0.f}};
  for (int kb = 0; kb < K; kb += 32) {
    s8v a = ldfrag(A, K, m0, kb, l);
#pragma unroll
    for (int nt = 0; nt < 4; nt++) {
      s8v b = ldfrag(Bm, K, n0 + nt * 16, kb, l);
      acc[nt] = __builtin_amdgcn_mfma_f32_16x16x32_bf16(a, b, acc[nt], 0, 0, 0);
    }
  }
  int rb = (l >> 4) * 4;
  int col = l & 15;
#pragma unroll
  for (int nt = 0; nt < 4; nt++) {
    int n = n0 + nt * 16 + col;
    float bv = bias ? bias[n] : 0.f;
#pragma unroll
    for (int i = 0; i < 4; i++) {
      int m = m0 + rb + i;
      float v = acc[nt][i] + bv;
      if (act) v = tanhf(v);
      size_t o = (size_t)m * N + n;
      if (outF) outF[o] = v;
      if (outB) outB[o] = f2b(v);
    }
  }
}

// ---------------- persistent sequential loop (cooperative, wide-poll flags) ----------------

struct LoopP {
  const ushort* whh0b; const ushort* gi0b; const ushort* wh2cb; const ushort* whh1b;
  const ushort* wcombb; const ushort* ctxpb; const ushort* ctxb;
  const float* bhh0; const float* bih1; const float* bhh1; const float* wmlp;
  const float* h0f; const ushort* h0b;
  float* h1f; ushort* h1b; float* hidf; float* gh1f; ushort* zrawb;
  float* H2f; ushort* H2b;
  unsigned* flags;   // 5 x 64 dwords: 0=fA 1=fH 2=fG 3=fZ 4=fD; memset 0 per launch
};

#define FA 0
#define FH 1
#define FG 2
#define FZ 3
#define FD 4
static __device__ __forceinline__ unsigned* flg(unsigned* base, int k) { return base + k * 64; }

// producer: drain data stores, then plain-store t+1 into own slot (no RMW)
static __device__ __forceinline__ void arrive(unsigned* slot, unsigned val) {
  asm volatile("s_waitcnt vmcnt(0)" ::: "memory");
  __syncthreads();
  if (threadIdx.x == 0) st_scu(slot, val);
}
// consumer: wave 0 polls all 64 producer slots with one 64-lane uncached load
static __device__ __forceinline__ void waitflag(const unsigned* slot64, unsigned tgt) {
  __syncthreads();
  if (threadIdx.x < 64) {
    for (;;) {
      unsigned v = ld_scu(slot64 + threadIdx.x);
      if (__all((int)(v >= tgt))) break;
      __builtin_amdgcn_s_sleep(1);
    }
  }
  __syncthreads();
}

// 3-accumulator MFMA batch (roles 0,1,3); stg[bb] must be constant-indexed
#define GRU_BATCH(bb, VMN) \
  do { VMW(VMN); \
    _Pragma("unroll") \
    for (int i = 0; i < 4; i++) { \
      int kb = (bb) * 128 + i * 32; \
      s8v av = stg[bb][i]; \
      aR = __builtin_amdgcn_mfma_f32_16x16x32_bf16(av, ldsfrag(ldsW, rr, kb, l), aR, 0, 0, 0); \
      aZ = __builtin_amdgcn_mfma_f32_16x16x32_bf16(av, ldsfrag(ldsW, 16 + rr, kb, l), aZ, 0, 0, 0); \
      aN = __builtin_amdgcn_mfma_f32_16x16x32_bf16(av, ldsfrag(ldsW, 32 + rr, kb, l), aN, 0, 0, 0); \
    } } while (0)

#define HID_BATCH(bb, VMN) \
  do { VMW(VMN); \
    _Pragma("unroll") \
    for (int i = 0; i < 4; i++) { \
      int kb = (bb) * 128 + i * 32; \
      acc = __builtin_amdgcn_mfma_f32_16x16x32_bf16(stg[bb][i], ldsfrag(ldsW, rr, kb, l), acc, 0, 0, 0); \
    } } while (0)

// roles: 0 (blk 0-63)=GRU0/Whh0 ; 1 (64-127)=GRU1/Wcomb ; 2 (128-191)=hid/Wh2c + attn ; 3 (192-255)=gh1/Whh1
__global__ __launch_bounds__(256) void k_loop(LoopP p) {
  __shared__ __align__(16) ushort ldsW[48 * 1024];   // 96KB, 48 rows x 2KB, XOR-swizzled
  __shared__ __align__(16) float hs[C_];
  __shared__ float sc[S_];
  __shared__ float al[S_];
  __shared__ __align__(8) ushort stile[64 * 16];     // bf16 epilogue re-layout tile

  const int tid = threadIdx.x;
  const int blk = blockIdx.x;
  const int l = tid & 63, w = tid >> 6;
  const int role = blk >> 6;
  const int sub = blk & 63;

  // ---- stage this block's weight slice into swizzled LDS (once) ----
  {
    const ushort* src;
    int nrows;
    if (role == 0)      { src = p.whh0b; nrows = 48; }
    else if (role == 1) { src = p.wcombb; nrows = 48; }
    else if (role == 2) { src = p.wh2cb; nrows = 16; }
    else                { src = p.whh1b; nrows = 48; }
    for (int idx = tid; idx < nrows * 128; idx += 256) {
      int r = idx >> 7, c = idx & 127;
      int grow;
      if (role == 0 || role == 1) grow = (r >> 4) * H_ + sub * 16 + (r & 15);
      else if (role == 2)         grow = sub * 16 + r;
      else                        grow = sub * 48 + r;
      s8v v = *reinterpret_cast<const s8v*>(src + (size_t)grow * 1024 + c * 8);
      unsigned o = (unsigned)r * 2048u + (((unsigned)(c * 16)) ^ ((unsigned)((r & 7) << 4)));
      *reinterpret_cast<s8v*>((char*)ldsW + o) = v;
    }
    __syncthreads();
  }

  const int rr = l & 15;
  const int m0 = w * 16;
  const int rb = (l >> 4) * 4, c15 = l & 15;

  for (int t = 0; t < TS_; t++) {
    if (role == 0) {
      // ---- phase A: h1 = GRU0(h_prev) ----
      if (t) waitflag(flg(p.flags, FD), (unsigned)t);
      const float*  hpf = t ? (p.H2f + (size_t)(t - 1) * B_ * H_) : p.h0f;
      const ushort* hpb = t ? (p.H2b + (size_t)(t - 1) * B_ * H_) : p.h0b;
      const ushort* gi0t = p.gi0b + (size_t)t * B_ * 3 * H_;
      const ushort* abase = hpb + (size_t)(m0 + (l & 15)) * H_ + ((l >> 4) << 3);
      s8v stg[8][4];
#pragma unroll
      for (int bb = 0; bb < 8; bb++)
        ld_b4(abase + bb * 128, stg[bb][0], stg[bb][1], stg[bb][2], stg[bb][3]);
      int c = sub * 16 + c15;
      float hp[4];
#pragma unroll
      for (int i = 0; i < 4; i++) hp[i] = ld_scf(&hpf[(size_t)(m0 + rb + i) * H_ + c]);
      f4v aR = {0.f,0.f,0.f,0.f}, aZ = {0.f,0.f,0.f,0.f}, aN = {0.f,0.f,0.f,0.f};
      GRU_BATCH(0, 32); GRU_BATCH(1, 28); GRU_BATCH(2, 24); GRU_BATCH(3, 20);
      GRU_BATCH(4, 16); GRU_BATCH(5, 12); GRU_BATCH(6, 8);  GRU_BATCH(7, 4);
      VMW(0);
#pragma unroll
      for (int i = 0; i < 4; i++) {
        int m = m0 + rb + i;
        const ushort* gi = gi0t + (size_t)m * (3 * H_);
        float gir = b2f(gi[c]), giz = b2f(gi[H_ + c]), gin = b2f(gi[2 * H_ + c]);
        float ghr = aR[i] + p.bhh0[c], ghz = aZ[i] + p.bhh0[H_ + c], ghn = aN[i] + p.bhh0[2 * H_ + c];
        float r = sigm(gir + ghr);
        float zg = sigm(giz + ghz);
        float nn = tanh_fast(gin + r * ghn);
        float h1 = (1.f - zg) * nn + zg * hp[i];
        st_scf(&p.h1f[(size_t)m * H_ + c], h1);
        stile[m * 16 + c15] = f2b(h1);
      }
      __syncthreads();
      {
        int row = tid >> 2, ch = tid & 3;
        unsigned long long v = *reinterpret_cast<unsigned long long*>(&stile[row * 16 + ch * 4]);
        st_sc8(&p.h1b[(size_t)row * H_ + sub * 16 + ch * 4], v);
      }
      arrive(flg(p.flags, FA) + sub, (unsigned)(t + 1));

    } else if (role == 2) {
      // ---- hid = h1 @ Wh2c.T (16-col slice) ----
      waitflag(flg(p.flags, FA), (unsigned)(t + 1));
      {
        const ushort* abase = p.h1b + (size_t)(m0 + (l & 15)) * H_ + ((l >> 4) << 3);
        s8v stg[8][4];
#pragma unroll
        for (int bb = 0; bb < 8; bb++)
          ld_b4(abase + bb * 128, stg[bb][0], stg[bb][1], stg[bb][2], stg[bb][3]);
        f4v acc = {0.f,0.f,0.f,0.f};
        HID_BATCH(0, 28); HID_BATCH(1, 24); HID_BATCH(2, 20); HID_BATCH(3, 16);
        HID_BATCH(4, 12); HID_BATCH(5, 8);  HID_BATCH(6, 4);  HID_BATCH(7, 0);
        int c = sub * 16 + c15;
#pragma unroll
        for (int i = 0; i < 4; i++) st_scf(&p.hidf[(size_t)(m0 + rb + i) * C_ + c], acc[i]);
      }
      arrive(flg(p.flags, FH) + sub, (unsigned)(t + 1));

      // ---- attention -> z_raw (b = sub) ----
      waitflag(flg(p.flags, FH), (unsigned)(t + 1));
      {
        int b = sub;
        f4v hv = ld_scf4(&p.hidf[(size_t)b * C_ + tid * 4]);
        VMW(0);
        *reinterpret_cast<f4v*>(&hs[tid * 4]) = hv;
        __syncthreads();
        for (int s = w; s < S_; s += 4) {
          const ushort* row = p.ctxpb + ((size_t)s * B_ + b) * C_;
          float a = 0.f;
          for (int c4 = l * 4; c4 < C_; c4 += 256) {
            ushort4 cv = *reinterpret_cast<const ushort4*>(row + c4);
            f4v hv4 = *reinterpret_cast<const f4v*>(&hs[c4]);
            float4 wv = *reinterpret_cast<const float4*>(p.wmlp + c4);
            a += tanh_fast(b2f(cv.x) + hv4[0]) * wv.x;
            a += tanh_fast(b2f(cv.y) + hv4[1]) * wv.y;
            a += tanh_fast(b2f(cv.z) + hv4[2]) * wv.z;
            a += tanh_fast(b2f(cv.w) + hv4[3]) * wv.w;
          }
          for (int m = 32; m; m >>= 1) a += __shfl_xor(a, m, 64);
          if (l == 0) sc[s] = a;
        }
        __syncthreads();
        float mx = -1e30f;
        for (int s = 0; s < S_; s++) mx = fmaxf(mx, sc[s]);
        float sm = 0.f;
        for (int s = 0; s < S_; s++) sm += __expf(sc[s] - mx);
        if (tid < S_) al[tid] = __expf(sc[tid] - mx) / sm;
        __syncthreads();
        int c0 = tid * 4;
        float a0 = 0.f, a1 = 0.f, a2 = 0.f, a3 = 0.f;
        for (int s = 0; s < S_; s++) {
          float a = al[s];
          ushort4 cv = *reinterpret_cast<const ushort4*>(p.ctxb + ((size_t)s * B_ + b) * C_ + c0);
          a0 += a * b2f(cv.x); a1 += a * b2f(cv.y); a2 += a * b2f(cv.z); a3 += a * b2f(cv.w);
        }
        ushort4 o; o.x = f2b(a0); o.y = f2b(a1); o.z = f2b(a2); o.w = f2b(a3);
        unsigned long long pk; __builtin_memcpy(&pk, &o, 8);
        st_sc8(p.zrawb + (size_t)b * C_ + c0, pk);
      }
      arrive(flg(p.flags, FZ) + sub, (unsigned)(t + 1));

    } else if (role == 3) {
      // ---- gh1 = h1 @ Whh1.T (48-col slice) ----
      waitflag(flg(p.flags, FA), (unsigned)(t + 1));
      {
        const ushort* abase = p.h1b + (size_t)(m0 + (l & 15)) * H_ + ((l >> 4) << 3);
        s8v stg[8][4];
#pragma unroll
        for (int bb = 0; bb < 8; bb++)
          ld_b4(abase + bb * 128, stg[bb][0], stg[bb][1], stg[bb][2], stg[bb][3]);
        f4v aR = {0.f,0.f,0.f,0.f}, aZ = {0.f,0.f,0.f,0.f}, aN = {0.f,0.f,0.f,0.f};
        GRU_BATCH(0, 28); GRU_BATCH(1, 24); GRU_BATCH(2, 20); GRU_BATCH(3, 16);
        GRU_BATCH(4, 12); GRU_BATCH(5, 8);  GRU_BATCH(6, 4);  GRU_BATCH(7, 0);
        int cb = sub * 48 + c15;
#pragma unroll
        for (int i = 0; i < 4; i++) {
          int m = m0 + rb + i;
          st_scf(&p.gh1f[(size_t)m * (3 * H_) + cb],      aR[i]);
          st_scf(&p.gh1f[(size_t)m * (3 * H_) + cb + 16], aZ[i]);
          st_scf(&p.gh1f[(size_t)m * (3 * H_) + cb + 32], aN[i]);
        }
      }
      arrive(flg(p.flags, FG) + sub, (unsigned)(t + 1));

    } else {
      // ---- role 1: h2 = GRU1(z_raw, h1) ----
      waitflag(flg(p.flags, FG), (unsigned)(t + 1));
      float* h2f = p.H2f + (size_t)t * B_ * H_;
      ushort* h2b = p.H2b + (size_t)t * B_ * H_;
      int c = sub * 16 + c15;
      float gr[4], gz[4], gn[4], h1v[4];
#pragma unroll
      for (int i = 0; i < 4; i++) {       // prefetch: overlaps the fZ wait
        int m = m0 + rb + i;
        gr[i]  = ld_scf(&p.gh1f[(size_t)m * (3 * H_) + c]);
        gz[i]  = ld_scf(&p.gh1f[(size_t)m * (3 * H_) + H_ + c]);
        gn[i]  = ld_scf(&p.gh1f[(size_t)m * (3 * H_) + 2 * H_ + c]);
        h1v[i] = ld_scf(&p.h1f[(size_t)m * H_ + c]);
      }
      waitflag(flg(p.flags, FZ), (unsigned)(t + 1));   // poll drains vmcnt -> gr/gz/gn/h1v ready
      const ushort* abase = p.zrawb + (size_t)(m0 + (l & 15)) * C_ + ((l >> 4) << 3);
      s8v stg[8][4];
#pragma unroll
      for (int bb = 0; bb < 8; bb++)
        ld_b4(abase + bb * 128, stg[bb][0], stg[bb][1], stg[bb][2], stg[bb][3]);
      f4v aR = {0.f,0.f,0.f,0.f}, aZ = {0.f,0.f,0.f,0.f}, aN = {0.f,0.f,0.f,0.f};
      GRU_BATCH(0, 28); GRU_BATCH(1, 24); GRU_BATCH(2, 20); GRU_BATCH(3, 16);
      GRU_BATCH(4, 12); GRU_BATCH(5, 8);  GRU_BATCH(6, 4);  GRU_BATCH(7, 0);
#pragma unroll
      for (int i = 0; i < 4; i++) {
        int m = m0 + rb + i;
        float gir = aR[i] + p.bih1[c], giz = aZ[i] + p.bih1[H_ + c], gin = aN[i] + p.bih1[2 * H_ + c];
        float ghr = gr[i] + p.bhh1[c], ghz = gz[i] + p.bhh1[H_ + c], ghn = gn[i] + p.bhh1[2 * H_ + c];
        float r = sigm(gir + ghr);
        float zg = sigm(giz + ghz);
        float nn = tanh_fast(gin + r * ghn);
        float h2 = (1.f - zg) * nn + zg * h1v[i];
        st_scf(&h2f[(size_t)m * H_ + c], h2);
        stile[m * 16 + c15] = f2b(h2);
      }
      __syncthreads();
      {
        int row = tid >> 2, ch = tid & 3;
        unsigned long long v = *reinterpret_cast<unsigned long long*>(&stile[row * 16 + ch * 4]);
        st_sc8(&h2b[(size_t)row * H_ + sub * 16 + ch * 4], v);
      }
      arrive(flg(p.flags, FD) + sub, (unsigned)(t + 1));
    }
  }
}

// ---------------- epilogue: streaming LSE over vocab ----------------
#define LSE_NCH 40
#define LSE_TILES 50    // 16-col tiles per chunk (40*50*16 = 32000)

__global__ __launch_bounds__(512) void k_lse2(const ushort* __restrict__ logitb,
                                              const ushort* __restrict__ wopb,
                                              const float* __restrict__ bop,
                                              float* __restrict__ part) {
  __shared__ ushort Bs[2][16 * E_];   // 2 x 16KB (16 rows x 1024B)
  int tid = threadIdx.x, l = tid & 63, w = tid >> 6;
  int r0 = blockIdx.y * 128 + w * 16;
  int c0 = blockIdx.x * (LSE_TILES * 16);
  int arow = r0 + (l & 15);
  bool aok = arow < NR_;

  s8v afr[16];
#pragma unroll
  for (int kk = 0; kk < 16; kk++) {
    s8v z = {0,0,0,0,0,0,0,0};
    afr[kk] = aok ? *reinterpret_cast<const s8v*>(logitb + (size_t)arow * E_ + kk * 32 + ((l >> 4) << 3)) : z;
  }

  const int srow = tid >> 5;
  const int scb = (tid & 31) * 32;
  const unsigned sxr = (unsigned)((srow & 7) << 4);
  char* sdst0 = (char*)&Bs[0][0] + srow * 1024;
  char* sdst1 = (char*)&Bs[1][0] + srow * 1024;

  const int brow = l & 15;
  const unsigned lanep = (unsigned)((l >> 4) << 4);
  const unsigned xorv = (unsigned)((brow & 7) << 4);
  const char* bbase0 = (const char*)&Bs[0][0] + brow * 1024;
  const char* bbase1 = (const char*)&Bs[1][0] + brow * 1024;

  f4v mr = {-1e30f, -1e30f, -1e30f, -1e30f};
  f4v sr = {0.f, 0.f, 0.f, 0.f};

  {
    const char* src = (const char*)(wopb + (size_t)(c0 + srow) * E_) + scb;
    s8v g0 = *reinterpret_cast<const s8v*>(src);
    s8v g1 = *reinterpret_cast<const s8v*>(src + 16);
    *reinterpret_cast<s8v*>(sdst0 + ((unsigned)scb ^ sxr)) = g0;
    *reinterpret_cast<s8v*>(sdst0 + (((unsigned)scb + 16u) ^ sxr)) = g1;
  }
  __syncthreads();

  for (int tt = 0; tt < LSE_TILES; tt++) {
    int cur = tt & 1;
    bool more = (tt + 1) < LSE_TILES;
    s8v g0, g1;
    if (more) {
      const char* src = (const char*)(wopb + (size_t)(c0 + (tt + 1) * 16 + srow) * E_) + scb;
      g0 = *reinterpret_cast<const s8v*>(src);
      g1 = *reinterpret_cast<const s8v*>(src + 16);
    }
    const char* bbase = cur ? bbase1 : bbase0;
    f4v acc = {0.f, 0.f, 0.f, 0.f};
#pragma unroll
    for (int kk = 0; kk < 16; kk++) {
      unsigned off = ((unsigned)(kk * 64) + lanep) ^ xorv;
      s8v b = *reinterpret_cast<const s8v*>(bbase + off);
      acc = __builtin_amdgcn_mfma_f32_16x16x32_bf16(afr[kk], b, acc, 0, 0, 0);
    }
    float bv = bop[c0 + tt * 16 + (l & 15)];
#pragma unroll
    for (int i = 0; i < 4; i++) {
      float v = acc[i] + bv;
      if (v <= mr[i]) {
        sr[i] += __expf(v - mr[i]);
      } else {
        sr[i] = sr[i] * __expf(mr[i] - v) + 1.f;
        mr[i] = v;
      }
    }
    if (more) {
      char* sdst = cur ? sdst0 : sdst1;
      *reinterpret_cast<s8v*>(sdst + ((unsigned)scb ^ sxr)) = g0;
      *reinterpret_cast<s8v*>(sdst + (((unsigned)scb + 16u) ^ sxr)) = g1;
      __syncthreads();
    }
  }

  for (int sh = 1; sh < 16; sh <<= 1) {
#pragma unroll
    for (int i = 0; i < 4; i++) {
      float om = __shfl_xor(mr[i], sh, 64);
      float os = __shfl_xor(sr[i], sh, 64);
      float mn = fmaxf(mr[i], om);
      sr[i] = sr[i] * __expf(mr[i] - mn) + os * __expf(om - mn);
      mr[i] = mn;
    }
  }
  if ((l & 15) == 0) {
#pragma unroll
    for (int i = 0; i < 4; i++) {
      int row = r0 + (l >> 4) * 4 + i;
      if (row < NR_) {
        size_t o = ((size_t)row * LSE_NCH + blockIdx.x) * 2;
        part[o] = mr[i];
        part[o + 1] = sr[i];
      }
    }
  }
}

__global__ void k_final(const float* __restrict__ part, const ushort* __restrict__ logitb,
                        const float* __restrict__ Wop, const float* __restrict__ bop,
                        const int* __restrict__ y, float* __restrict__ nll) {
  int i = blockIdx.x * 256 + threadIdx.x;
  if (i >= NR_) return;
  float m = -1e30f;
  for (int c = 0; c < LSE_NCH; c++) m = fmaxf(m, part[((size_t)i * LSE_NCH + c) * 2]);
  float s = 0.f;
  for (int c = 0; c < LSE_NCH; c++) {
    size_t o = ((size_t)i * LSE_NCH + c) * 2;
    s += part[o + 1] * __expf(part[o] - m);
  }
  float lse = m + logf(s);
  int tgt = y[i + B_];
  float v = 0.f;
  if (tgt != 0) {
    const ushort* lr = logitb + (size_t)i * E_;
    const float* wr = Wop + (size_t)tgt * E_;
    float dot = 0.f;
    for (int k = 0; k < E_; k += 4) {
      ushort4 lv = *reinterpret_cast<const ushort4*>(lr + k);
      float4 wv = *reinterpret_cast<const float4*>(wr + k);
      dot += b2f(lv.x) * wv.x + b2f(lv.y) * wv.y + b2f(lv.z) * wv.z + b2f(lv.w) * wv.w;
    }
    dot += bop[tgt];
    v = lse - dot;
  }
  nll[i] = v;
}

__global__ void k_reduce(const float* __restrict__ nll, float* __restrict__ out) {
  __shared__ float sh[256];
  float a = 0.f;
  for (int i = threadIdx.x; i < NR_; i += 256) a += nll[i];
  sh[threadIdx.x] = a;
  __syncthreads();
  for (int s = 128; s; s >>= 1) {
    if (threadIdx.x < s) sh[threadIdx.x] += sh[threadIdx.x + s];
    __syncthreads();
  }
  if (threadIdx.x == 0) out[0] = sh[0];
}

// ---------------- host ----------------

extern "C" void kernel_launch(void* const* d_in, const int* in_sizes, int n_in,
                              void* d_out, int out_size, void* d_ws, size_t ws_size,
                              hipStream_t stream) {
  const float* ctx  = (const float*)d_in[0];
  const int*   y    = (const int*)d_in[1];
  const float* emb  = (const float*)d_in[2];
  const float* Wih0 = (const float*)d_in[3];
  const float* Whh0 = (const float*)d_in[4];
  const float* bih0 = (const float*)d_in[5];
  const float* bhh0 = (const float*)d_in[6];
  const float* Wih1 = (const float*)d_in[7];
  const float* Whh1 = (const float*)d_in[8];
  const float* bih1 = (const float*)d_in[9];
  const float* bhh1 = (const float*)d_in[10];
  const float* Wc2c = (const float*)d_in[11];
  const float* Wh2c = (const float*)d_in[12];
  const float* wmlp = (const float*)d_in[13];
  const float* Wc2h = (const float*)d_in[14];
  const float* Who  = (const float*)d_in[15];
  const float* bho  = (const float*)d_in[16];
  const float* Wop  = (const float*)d_in[17];
  const float* bop  = (const float*)d_in[18];

  char* ws = (char*)d_ws;
  size_t off = 0;
  auto alloc = [&](size_t bytes) { void* p = ws + off; off += (bytes + 255) & ~size_t(255); return p; };

  ushort* ctxb   = (ushort*)alloc((size_t)S_ * B_ * C_ * 2);
  ushort* wih0b  = (ushort*)alloc((size_t)3 * H_ * E_ * 2);
  ushort* whh0b  = (ushort*)alloc((size_t)3 * H_ * H_ * 2);
  ushort* wh2cb  = (ushort*)alloc((size_t)C_ * H_ * 2);
  ushort* wc2hT  = (ushort*)alloc((size_t)C_ * H_ * 2);
  ushort* wih1b  = (ushort*)alloc((size_t)3 * H_ * H_ * 2);
  ushort* whh1b  = (ushort*)alloc((size_t)3 * H_ * H_ * 2);
  ushort* whob   = (ushort*)alloc((size_t)E_ * H_ * 2);
  ushort* wopb   = (ushort*)alloc((size_t)V_ * E_ * 2);
  ushort* wc2cb  = (ushort*)alloc((size_t)C_ * C_ * 2);
  ushort* wcombb = (ushort*)alloc((size_t)3 * H_ * C_ * 2);
  ushort* xb     = (ushort*)alloc((size_t)NR_ * E_ * 2);
  ushort* gi0b   = (ushort*)alloc((size_t)NR_ * 3 * H_ * 2);
  ushort* ctxpb  = (ushort*)alloc((size_t)S_ * B_ * C_ * 2);
  float*  H2f    = (float*)alloc((size_t)TS_ * B_ * H_ * 4);
  ushort* H2b    = (ushort*)alloc((size_t)TS_ * B_ * H_ * 2);
  float*  h0f    = (float*)alloc((size_t)B_ * H_ * 4);
  ushort* h0b    = (ushort*)alloc((size_t)B_ * H_ * 2);
  float*  h1f    = (float*)alloc((size_t)B_ * H_ * 4);
  ushort* h1b    = (ushort*)alloc((size_t)B_ * H_ * 2);
  float*  hidf   = (float*)alloc((size_t)B_ * C_ * 4);
  float*  gh1f   = (float*)alloc((size_t)B_ * 3 * H_ * 4);
  ushort* zrawb  = (ushort*)alloc((size_t)B_ * C_ * 2);
  ushort* logitb = (ushort*)alloc((size_t)NR_ * E_ * 2);
  float*  part   = (float*)alloc((size_t)2048 * LSE_NCH * 2 * 4);
  float*  nllb   = (float*)alloc((size_t)2048 * 4);
  unsigned* flags = (unsigned*)alloc(5 * 64 * 4);
  (void)ws_size; (void)in_sizes; (void)n_in; (void)out_size;

  (void)hipMemsetAsync(h0f, 0, (size_t)B_ * H_ * 4, stream);
  (void)hipMemsetAsync(h0b, 0, (size_t)B_ * H_ * 2, stream);
  (void)hipMemsetAsync(flags, 0, 5 * 64 * 4, stream);

  auto cgrid = [](int n) { return dim3((unsigned)((n / 4 + 255) / 256)); };
  k_convert<<<cgrid(S_ * B_ * C_), 256, 0, stream>>>(ctx, ctxb, S_ * B_ * C_);
  k_convert<<<cgrid(3 * H_ * E_), 256, 0, stream>>>(Wih0, wih0b, 3 * H_ * E_);
  k_convert<<<cgrid(3 * H_ * H_), 256, 0, stream>>>(Whh0, whh0b, 3 * H_ * H_);
  k_convert<<<cgrid(C_ * H_), 256, 0, stream>>>(Wh2c, wh2cb, C_ * H_);
  k_convert<<<cgrid(3 * H_ * H_), 256, 0, stream>>>(Wih1, wih1b, 3 * H_ * H_);
  k_convert<<<cgrid(3 * H_ * H_), 256, 0, stream>>>(Whh1, whh1b, 3 * H_ * H_);
  k_convert<<<cgrid(E_ * H_), 256, 0, stream>>>(Who, whob, E_ * H_);
  k_convert<<<cgrid(V_ * E_), 256, 0, stream>>>(Wop, wopb, V_ * E_);
  k_convert<<<cgrid(C_ * C_), 256, 0, stream>>>(Wc2c, wc2cb, C_ * C_);
  k_convert_T<<<dim3(4096), 256, 0, stream>>>(Wc2h, wc2hT);

  k_gather<<<dim3((NR_ * (E_ / 4) + 255) / 256), 256, 0, stream>>>(y, emb, xb);

  gemm_bt<<<dim3(3 * H_ / 64, NR_ / 64), 256, 0, stream>>>(xb, wih0b, bih0, nullptr, gi0b,
                                                           NR_, 3 * H_, E_, 0);
  gemm_bt<<<dim3(C_ / 64, S_ * B_ / 64), 256, 0, stream>>>(ctxb, wc2cb, nullptr, nullptr, ctxpb,
                                                           S_ * B_, C_, C_, 0);
  gemm_bt<<<dim3(C_ / 64, 3 * H_ / 64), 256, 0, stream>>>(wih1b, wc2hT, nullptr, nullptr, wcombb,
                                                          3 * H_, C_, H_, 0);

  LoopP p;
  p.whh0b = whh0b; p.gi0b = gi0b; p.wh2cb = wh2cb; p.whh1b = whh1b;
  p.wcombb = wcombb; p.ctxpb = ctxpb; p.ctxb = ctxb;
  p.bhh0 = bhh0; p.bih1 = bih1; p.bhh1 = bhh1; p.wmlp = wmlp;
  p.h0f = h0f; p.h0b = h0b;
  p.h1f = h1f; p.h1b = h1b; p.hidf = hidf; p.gh1f = gh1f; p.zrawb = zrawb;
  p.H2f = H2f; p.H2b = H2b; p.flags = flags;
  void* args[] = { (void*)&p };
  (void)hipLaunchCooperativeKernel(k_loop, dim3(NBLK_), dim3(256), args, 0, stream);

  gemm_bt<<<dim3(E_ / 64, NR_ / 64), 256, 0, stream>>>(H2b, whob, bho, nullptr, logitb,
                                                       NR_, E_, H_, 1);
  k_lse2<<<dim3(LSE_NCH, 16), 512, 0, stream>>>(logitb, wopb, bop, part);
  k_final<<<dim3(8), 256, 0, stream>>>(part, logitb, Wop, bop, y, nllb);
  k_reduce<<<dim3(1), 256, 0, stream>>>(nllb, (float*)d_out);
}